// Round 5
// baseline (254.140 us; speedup 1.0000x reference)
//
#include <hip/hip_runtime.h>
#include <hip/hip_bf16.h>
#include <stdint.h>

// Problem constants
#define D_MODEL 1024
#define NHEADS  16
#define DKH     64
#define BATCH   4
#define SEQ     2048
#define NTOK    (BATCH * SEQ)   // 8192

typedef unsigned short u16;
using bf16x8 = __attribute__((ext_vector_type(8))) short;   // 8 bf16 = 4 VGPR (MFMA A/B frag)
using f32x4  = __attribute__((ext_vector_type(4))) float;   // MFMA C/D frag

// async global->LDS, 16B per lane; LDS dest is wave-uniform base (+lane*16 by HW)
#define GLD16(g, l)                                                            \
  __builtin_amdgcn_global_load_lds(                                            \
      (const __attribute__((address_space(1))) void*)(g),                      \
      (__attribute__((address_space(3))) void*)(l), 16, 0, 0)

__device__ inline u16 f2bf(float f) {
  __hip_bfloat16 h = __float2bfloat16(f);
  return __builtin_bit_cast(u16, h);
}

// ---------------------------------------------------------------- fused converts
__global__ __launch_bounds__(256) void cvt_all(const float* __restrict__ x,
                                               const float* __restrict__ wq,
                                               const float* __restrict__ wk,
                                               const float* __restrict__ wv,
                                               const float* __restrict__ wo,
                                               u16* xb, u16* wqb, u16* wkb, u16* wvb, u16* wob) {
  const int XC = NTOK * D_MODEL / 4;      // 2097152
  const int WC = D_MODEL * D_MODEL / 4;   // 262144
  const int total = XC + 4 * WC;
  for (int i = blockIdx.x * 256 + threadIdx.x; i < total; i += gridDim.x * 256) {
    const float4* s; ushort4* d; int j;
    if (i < XC)              { s = (const float4*)x;  d = (ushort4*)xb;  j = i; }
    else if (i < XC + WC)    { s = (const float4*)wq; d = (ushort4*)wqb; j = i - XC; }
    else if (i < XC + 2*WC)  { s = (const float4*)wk; d = (ushort4*)wkb; j = i - XC - WC; }
    else if (i < XC + 3*WC)  { s = (const float4*)wv; d = (ushort4*)wvb; j = i - XC - 2*WC; }
    else                     { s = (const float4*)wo; d = (ushort4*)wob; j = i - XC - 3*WC; }
    float4 v = s[j];
    d[j] = make_ushort4(f2bf(v.x), f2bf(v.y), f2bf(v.z), f2bf(v.w));
  }
}

// ---------------------------------------------------------------- fused QKV projection
// A [NTOK,D] bf16; Bq/Bk/Bv [D,D] bf16 (nn.Linear layout, C = A*B^T).
// z=0: Q out, scaled 0.125*log2(e) (exp2-domain softmax). z=1: K. z=2: V transposed per-head.
__global__ __launch_bounds__(256) void gemm_qkv(const u16* __restrict__ A,
                                                const u16* __restrict__ Bq,
                                                const u16* __restrict__ Bk,
                                                const u16* __restrict__ Bv,
                                                u16* __restrict__ Qo,
                                                u16* __restrict__ Ko,
                                                u16* __restrict__ Vo) {
  __shared__ u16 As[128 * 64];
  __shared__ u16 Bs[128 * 64];
  const int z = blockIdx.z;
  const u16* __restrict__ Bp = z == 0 ? Bq : (z == 1 ? Bk : Bv);
  const int t = threadIdx.x, lane = t & 63, wave = t >> 6;
  const int wr = wave >> 1, wc = wave & 1;
  const int frow = lane & 15, fk = (lane >> 4) * 8;
  const int bM = blockIdx.y * 128, bN = blockIdx.x * 128;

  f32x4 acc[4][4] = {};

  for (int k0 = 0; k0 < D_MODEL; k0 += 64) {
    __syncthreads();
#pragma unroll
    for (int p = 0; p < 4; ++p) {
      int chunk = p * 256 + t;
      int r = chunk >> 3, cc = chunk & 7;
      GLD16(A + (size_t)(bM + r) * D_MODEL + k0 + cc * 8, As + (size_t)(p * 256 + (t & ~63)) * 8);
      GLD16(Bp + (size_t)(bN + r) * D_MODEL + k0 + cc * 8, Bs + (size_t)(p * 256 + (t & ~63)) * 8);
    }
    __syncthreads();

    bf16x8 a[2][4], b[2][4];
#pragma unroll
    for (int kk = 0; kk < 2; ++kk) {
#pragma unroll
      for (int m = 0; m < 4; ++m)
        a[kk][m] = *(const bf16x8*)&As[(wr * 64 + m * 16 + frow) * 64 + kk * 32 + fk];
#pragma unroll
      for (int n = 0; n < 4; ++n)
        b[kk][n] = *(const bf16x8*)&Bs[(wc * 64 + n * 16 + frow) * 64 + kk * 32 + fk];
    }
#pragma unroll
    for (int kk = 0; kk < 2; ++kk)
#pragma unroll
      for (int m = 0; m < 4; ++m)
#pragma unroll
        for (int n = 0; n < 4; ++n)
          acc[m][n] = __builtin_amdgcn_mfma_f32_16x16x32_bf16(a[kk][m], b[kk][n], acc[m][n], 0, 0, 0);
  }

  const int r0 = bM + wr * 64 + (lane >> 4) * 4;
  const int c0 = bN + wc * 64 + (lane & 15);
  if (z == 2) {
#pragma unroll
    for (int m = 0; m < 4; ++m)
#pragma unroll
      for (int n = 0; n < 4; ++n) {
        int r = r0 + m * 16;   // token (4-aligned, j stays in one batch)
        int cc = c0 + n * 16;  // d_model col
        size_t off = ((size_t)(r >> 11) * D_MODEL + cc) * SEQ + (r & (SEQ - 1));
        *(ushort4*)(Vo + off) = make_ushort4(f2bf(acc[m][n][0]), f2bf(acc[m][n][1]),
                                             f2bf(acc[m][n][2]), f2bf(acc[m][n][3]));
      }
  } else {
    u16* C = z ? Ko : Qo;
    const float sc = z ? 1.0f : 0.18033688f;  // (1/8)*log2(e): softmax in exp2 domain
#pragma unroll
    for (int m = 0; m < 4; ++m)
#pragma unroll
      for (int n = 0; n < 4; ++n)
#pragma unroll
        for (int j = 0; j < 4; ++j)
          C[(size_t)(r0 + m * 16 + j) * D_MODEL + (c0 + n * 16)] = f2bf(acc[m][n][j] * sc);
  }
}

// ---------------------------------------------------------------- output projection C = A*B^T, f32 out
__global__ __launch_bounds__(256) void gemm_out(const u16* __restrict__ A,
                                                const u16* __restrict__ B,
                                                float* __restrict__ C) {
  __shared__ u16 As[128 * 64];
  __shared__ u16 Bs[128 * 64];
  const int t = threadIdx.x, lane = t & 63, wave = t >> 6;
  const int wr = wave >> 1, wc = wave & 1;
  const int frow = lane & 15, fk = (lane >> 4) * 8;
  const int bM = blockIdx.y * 128, bN = blockIdx.x * 128;

  f32x4 acc[4][4] = {};

  for (int k0 = 0; k0 < D_MODEL; k0 += 64) {
    __syncthreads();
#pragma unroll
    for (int p = 0; p < 4; ++p) {
      int chunk = p * 256 + t;
      int r = chunk >> 3, cc = chunk & 7;
      GLD16(A + (size_t)(bM + r) * D_MODEL + k0 + cc * 8, As + (size_t)(p * 256 + (t & ~63)) * 8);
      GLD16(B + (size_t)(bN + r) * D_MODEL + k0 + cc * 8, Bs + (size_t)(p * 256 + (t & ~63)) * 8);
    }
    __syncthreads();

    bf16x8 a[2][4], b[2][4];
#pragma unroll
    for (int kk = 0; kk < 2; ++kk) {
#pragma unroll
      for (int m = 0; m < 4; ++m)
        a[kk][m] = *(const bf16x8*)&As[(wr * 64 + m * 16 + frow) * 64 + kk * 32 + fk];
#pragma unroll
      for (int n = 0; n < 4; ++n)
        b[kk][n] = *(const bf16x8*)&Bs[(wc * 64 + n * 16 + frow) * 64 + kk * 32 + fk];
    }
#pragma unroll
    for (int kk = 0; kk < 2; ++kk)
#pragma unroll
      for (int m = 0; m < 4; ++m)
#pragma unroll
        for (int n = 0; n < 4; ++n)
          acc[m][n] = __builtin_amdgcn_mfma_f32_16x16x32_bf16(a[kk][m], b[kk][n], acc[m][n], 0, 0, 0);
  }

  const int r0 = bM + wr * 64 + (lane >> 4) * 4;
  const int c0 = bN + wc * 64 + (lane & 15);
#pragma unroll
  for (int m = 0; m < 4; ++m)
#pragma unroll
    for (int n = 0; n < 4; ++n)
#pragma unroll
      for (int j = 0; j < 4; ++j)
        C[(size_t)(r0 + m * 16 + j) * D_MODEL + (c0 + n * 16)] = acc[m][n][j];
}

// ---------------------------------------------------------------- flash attention (causal)
// Q (pre-scaled 0.125*log2e), K: bf16 [NTOK, D_MODEL]; Vt: bf16 [B*H*64][SEQ];
// O: bf16 [NTOK, D_MODEL].
// BARRIER-FREE: one wave per block (64 thr), 32 q-rows each; K and V^T MFMA fragments
// loaded directly global->register (KV per (b,h) = 512KB, L2-resident; same-bh blocks
// land on one XCD). P goes through a 2KB wave-private LDS roundtrip (in-order DS ops).
// Softmax in exp2 domain with defer-max (T13).
__global__ __launch_bounds__(64, 3) void attn_fwd(const u16* __restrict__ Q,
                                                  const u16* __restrict__ K,
                                                  const u16* __restrict__ Vt,
                                                  u16* __restrict__ O) {
  __shared__ u16 Pl[16 * 64];   // 2 KB

  const int lane = threadIdx.x;
  const int c = lane & 15, g = lane >> 4;
  const int bh = blockIdx.x & 63;           // same-bh blocks: blockIdx % 8 const -> one XCD
  const int qi = blockIdx.x >> 6;           // 0..63, heavy-first
  const int qtile = 15 - (qi >> 2);
  const int ws = qi & 3;
  const int qw = qtile * 128 + ws * 32;
  const size_t rowbase = (size_t)(bh >> 4) * SEQ;
  const int hcol = (bh & 15) * DKH;
  const size_t vbase = (size_t)bh * DKH;
  const int nit = (qw >> 6) + 1;            // KV tiles this wave participates in

  // Q fragments in registers for the whole kernel
  bf16x8 qf[2][2];
#pragma unroll
  for (int m = 0; m < 2; ++m)
#pragma unroll
    for (int kk = 0; kk < 2; ++kk)
      qf[m][kk] = *(const bf16x8*)&Q[(rowbase + qw + m * 16 + c) * D_MODEL + hcol + kk * 32 + g * 8];

  f32x4 ot[4][2] = {};              // O^T[d_local][q]
  float mstate[2] = {-__builtin_inff(), -__builtin_inff()};
  float lstate[2] = {0.f, 0.f};

  for (int it = 0; it < nit; ++it) {
    const int kv0 = it * 64;

    // ---- K fragments direct from global (L2): rows k=n*16+c, cols kk*32+g*8
    bf16x8 kf[4][2];
#pragma unroll
    for (int n = 0; n < 4; ++n)
#pragma unroll
      for (int kk = 0; kk < 2; ++kk)
        kf[n][kk] = *(const bf16x8*)&K[(rowbase + kv0 + n * 16 + c) * D_MODEL + hcol + kk * 32 + g * 8];

    // ---- S^T = K Q^T (exp2-domain scores)
    f32x4 s[4][2] = {};
    __builtin_amdgcn_s_setprio(1);
#pragma unroll
    for (int kk = 0; kk < 2; ++kk)
#pragma unroll
      for (int n = 0; n < 4; ++n)
#pragma unroll
        for (int m = 0; m < 2; ++m)
          s[n][m] = __builtin_amdgcn_mfma_f32_16x16x32_bf16(kf[n][kk], qf[m][kk], s[n][m], 0, 0, 0);
    __builtin_amdgcn_s_setprio(0);

    // ---- V^T fragments direct from global; latency hides under softmax VALU
    bf16x8 vf[4][2];
#pragma unroll
    for (int d = 0; d < 4; ++d)
#pragma unroll
      for (int kk = 0; kk < 2; ++kk)
        vf[d][kk] = *(const bf16x8*)&Vt[(vbase + d * 16 + c) * SEQ + kv0 + kk * 32 + g * 8];

    const bool need_mask = (kv0 + 63 > qw);
#pragma unroll
    for (int m = 0; m < 2; ++m) {
      const int qg = qw + m * 16 + c;
      if (need_mask) {
#pragma unroll
        for (int n = 0; n < 4; ++n)
#pragma unroll
          for (int j2 = 0; j2 < 4; ++j2)
            if (kv0 + n * 16 + g * 4 + j2 > qg) s[n][m][j2] = -__builtin_inff();
      }
      float pmax = fmaxf(fmaxf(s[0][m][0], s[0][m][1]), fmaxf(s[0][m][2], s[0][m][3]));
#pragma unroll
      for (int n = 1; n < 4; ++n)
        pmax = fmaxf(pmax, fmaxf(fmaxf(s[n][m][0], s[n][m][1]), fmaxf(s[n][m][2], s[n][m][3])));
      pmax = fmaxf(pmax, __shfl_xor(pmax, 16));
      pmax = fmaxf(pmax, __shfl_xor(pmax, 32));
      // defer-max (T13), log2 domain: P bounded by 2^11.54 = e^8
      if (__any(pmax > mstate[m] + 11.5416f)) {
        float mnew = fmaxf(mstate[m], pmax);
        float al = exp2f(mstate[m] - mnew);  // first tile: exp2(-inf)=0
        mstate[m] = mnew;
        lstate[m] *= al;
#pragma unroll
        for (int d = 0; d < 4; ++d)
#pragma unroll
          for (int j2 = 0; j2 < 4; ++j2) ot[d][m][j2] *= al;
      }
      const float mm = mstate[m];
      float lsum = 0.f;
#pragma unroll
      for (int n = 0; n < 4; ++n) {
        float p0 = exp2f(s[n][m][0] - mm);
        float p1 = exp2f(s[n][m][1] - mm);
        float p2 = exp2f(s[n][m][2] - mm);
        float p3 = exp2f(s[n][m][3] - mm);
        lsum += (p0 + p1) + (p2 + p3);
        // P[q=c][k=n*16+g*4+j], 16B-chunk XOR swizzle by row&7
        *(ushort4*)&Pl[c * 64 + (((n * 2 + (g >> 1)) ^ (c & 7)) * 8) + (g & 1) * 4] =
            make_ushort4(f2bf(p0), f2bf(p1), f2bf(p2), f2bf(p3));
      }
      lsum += __shfl_xor(lsum, 16);
      lsum += __shfl_xor(lsum, 32);
      lstate[m] += lsum;

      // ---- O^T[.,m] += V^T P^T (wave-private LDS roundtrip; in-order DS ops)
      bf16x8 pf[2];
#pragma unroll
      for (int kk = 0; kk < 2; ++kk)
        pf[kk] = *(const bf16x8*)&Pl[c * 64 + (((g + 4 * kk) ^ (c & 7)) * 8)];
      __builtin_amdgcn_s_setprio(1);
#pragma unroll
      for (int kk = 0; kk < 2; ++kk)
#pragma unroll
        for (int d = 0; d < 4; ++d)
          ot[d][m] = __builtin_amdgcn_mfma_f32_16x16x32_bf16(vf[d][kk], pf[kk], ot[d][m], 0, 0, 0);
      __builtin_amdgcn_s_setprio(0);
    }
  }

  // ---- epilogue: O[q][d] = O^T/l
#pragma unroll
  for (int m = 0; m < 2; ++m) {
    float inv = 1.0f / lstate[m];
#pragma unroll
    for (int d = 0; d < 4; ++d) {
      ushort4 o4 = make_ushort4(f2bf(ot[d][m][0] * inv), f2bf(ot[d][m][1] * inv),
                                f2bf(ot[d][m][2] * inv), f2bf(ot[d][m][3] * inv));
      *(ushort4*)&O[(rowbase + qw + m * 16 + c) * D_MODEL + hcol + d * 16 + g * 4] = o4;
    }
  }
}

// ---------------------------------------------------------------- launch
extern "C" void kernel_launch(void* const* d_in, const int* in_sizes, int n_in,
                              void* d_out, int out_size, void* d_ws, size_t ws_size,
                              hipStream_t stream) {
  const float* x  = (const float*)d_in[0];
  const float* Wq = (const float*)d_in[1];
  const float* Wk = (const float*)d_in[2];
  const float* Wv = (const float*)d_in[3];
  const float* Wo = (const float*)d_in[4];
  float* out = (float*)d_out;

  u16* ws  = (u16*)d_ws;
  u16* xb  = ws;
  u16* wqb = xb + (size_t)NTOK * D_MODEL;
  u16* wkb = wqb + (size_t)D_MODEL * D_MODEL;
  u16* wvb = wkb + (size_t)D_MODEL * D_MODEL;
  u16* wob = wvb + (size_t)D_MODEL * D_MODEL;
  u16* Qb  = wob + (size_t)D_MODEL * D_MODEL;
  u16* Kb  = Qb + (size_t)NTOK * D_MODEL;
  u16* Vb  = Kb + (size_t)NTOK * D_MODEL;   // per-head V^T [B*H*64][SEQ]
  u16* Ob  = xb;  // reuse x's bf16 buffer after projections

  cvt_all<<<2048, 256, 0, stream>>>(x, Wq, Wk, Wv, Wo, xb, wqb, wkb, wvb, wob);

  gemm_qkv<<<dim3(D_MODEL / 128, NTOK / 128, 3), 256, 0, stream>>>(xb, wqb, wkb, wvb, Qb, Kb, Vb);

  attn_fwd<<<dim3(64 * 64), 64, 0, stream>>>(Qb, Kb, Vb, Ob);

  gemm_out<<<dim3(D_MODEL / 128, NTOK / 128), 256, 0, stream>>>(Ob, wob, out);
}

// Round 6
// 234.344 us; speedup vs baseline: 1.0845x; 1.0845x over previous
//
#include <hip/hip_runtime.h>
#include <hip/hip_bf16.h>
#include <stdint.h>

// Problem constants
#define D_MODEL 1024
#define NHEADS  16
#define DKH     64
#define BATCH   4
#define SEQ     2048
#define NTOK    (BATCH * SEQ)   // 8192

typedef unsigned short u16;
using bf16x8 = __attribute__((ext_vector_type(8))) short;   // 8 bf16 = 4 VGPR (MFMA A/B frag)
using f32x4  = __attribute__((ext_vector_type(4))) float;   // MFMA C/D frag

// async global->LDS, 16B per lane; LDS dest is wave-uniform base (+lane*16 by HW)
#define GLD16(g, l)                                                            \
  __builtin_amdgcn_global_load_lds(                                            \
      (const __attribute__((address_space(1))) void*)(g),                      \
      (__attribute__((address_space(3))) void*)(l), 16, 0, 0)

__device__ inline u16 f2bf(float f) {
  __hip_bfloat16 h = __float2bfloat16(f);
  return __builtin_bit_cast(u16, h);
}

// ---------------------------------------------------------------- fused converts
__global__ __launch_bounds__(256) void cvt_all(const float* __restrict__ x,
                                               const float* __restrict__ wq,
                                               const float* __restrict__ wk,
                                               const float* __restrict__ wv,
                                               const float* __restrict__ wo,
                                               u16* xb, u16* wqb, u16* wkb, u16* wvb, u16* wob) {
  const int XC = NTOK * D_MODEL / 4;      // 2097152
  const int WC = D_MODEL * D_MODEL / 4;   // 262144
  const int total = XC + 4 * WC;
  for (int i = blockIdx.x * 256 + threadIdx.x; i < total; i += gridDim.x * 256) {
    const float4* s; ushort4* d; int j;
    if (i < XC)              { s = (const float4*)x;  d = (ushort4*)xb;  j = i; }
    else if (i < XC + WC)    { s = (const float4*)wq; d = (ushort4*)wqb; j = i - XC; }
    else if (i < XC + 2*WC)  { s = (const float4*)wk; d = (ushort4*)wkb; j = i - XC - WC; }
    else if (i < XC + 3*WC)  { s = (const float4*)wv; d = (ushort4*)wvb; j = i - XC - 2*WC; }
    else                     { s = (const float4*)wo; d = (ushort4*)wob; j = i - XC - 3*WC; }
    float4 v = s[j];
    d[j] = make_ushort4(f2bf(v.x), f2bf(v.y), f2bf(v.z), f2bf(v.w));
  }
}

// ---------------------------------------------------------------- fused QKV projection
// A [NTOK,D] bf16; Bq/Bk/Bv [D,D] bf16 (nn.Linear layout, C = A*B^T).
// z=0: Q out, scaled 0.125*log2(e) (exp2-domain softmax). z=1: K. z=2: V transposed per-head.
__global__ __launch_bounds__(256) void gemm_qkv(const u16* __restrict__ A,
                                                const u16* __restrict__ Bq,
                                                const u16* __restrict__ Bk,
                                                const u16* __restrict__ Bv,
                                                u16* __restrict__ Qo,
                                                u16* __restrict__ Ko,
                                                u16* __restrict__ Vo) {
  __shared__ u16 As[128 * 64];
  __shared__ u16 Bs[128 * 64];
  const int z = blockIdx.z;
  const u16* __restrict__ Bp = z == 0 ? Bq : (z == 1 ? Bk : Bv);
  const int t = threadIdx.x, lane = t & 63, wave = t >> 6;
  const int wr = wave >> 1, wc = wave & 1;
  const int frow = lane & 15, fk = (lane >> 4) * 8;
  const int bM = blockIdx.y * 128, bN = blockIdx.x * 128;

  f32x4 acc[4][4] = {};

  for (int k0 = 0; k0 < D_MODEL; k0 += 64) {
    __syncthreads();
#pragma unroll
    for (int p = 0; p < 4; ++p) {
      int chunk = p * 256 + t;
      int r = chunk >> 3, cc = chunk & 7;
      GLD16(A + (size_t)(bM + r) * D_MODEL + k0 + cc * 8, As + (size_t)(p * 256 + (t & ~63)) * 8);
      GLD16(Bp + (size_t)(bN + r) * D_MODEL + k0 + cc * 8, Bs + (size_t)(p * 256 + (t & ~63)) * 8);
    }
    __syncthreads();

    bf16x8 a[2][4], b[2][4];
#pragma unroll
    for (int kk = 0; kk < 2; ++kk) {
#pragma unroll
      for (int m = 0; m < 4; ++m)
        a[kk][m] = *(const bf16x8*)&As[(wr * 64 + m * 16 + frow) * 64 + kk * 32 + fk];
#pragma unroll
      for (int n = 0; n < 4; ++n)
        b[kk][n] = *(const bf16x8*)&Bs[(wc * 64 + n * 16 + frow) * 64 + kk * 32 + fk];
    }
#pragma unroll
    for (int kk = 0; kk < 2; ++kk)
#pragma unroll
      for (int m = 0; m < 4; ++m)
#pragma unroll
        for (int n = 0; n < 4; ++n)
          acc[m][n] = __builtin_amdgcn_mfma_f32_16x16x32_bf16(a[kk][m], b[kk][n], acc[m][n], 0, 0, 0);
  }

  const int r0 = bM + wr * 64 + (lane >> 4) * 4;
  const int c0 = bN + wc * 64 + (lane & 15);
  if (z == 2) {
#pragma unroll
    for (int m = 0; m < 4; ++m)
#pragma unroll
      for (int n = 0; n < 4; ++n) {
        int r = r0 + m * 16;   // token (4-aligned, j stays in one batch)
        int cc = c0 + n * 16;  // d_model col
        size_t off = ((size_t)(r >> 11) * D_MODEL + cc) * SEQ + (r & (SEQ - 1));
        *(ushort4*)(Vo + off) = make_ushort4(f2bf(acc[m][n][0]), f2bf(acc[m][n][1]),
                                             f2bf(acc[m][n][2]), f2bf(acc[m][n][3]));
      }
  } else {
    u16* C = z ? Ko : Qo;
    const float sc = z ? 1.0f : 0.18033688f;  // (1/8)*log2(e): softmax in exp2 domain
#pragma unroll
    for (int m = 0; m < 4; ++m)
#pragma unroll
      for (int n = 0; n < 4; ++n)
#pragma unroll
        for (int j = 0; j < 4; ++j)
          C[(size_t)(r0 + m * 16 + j) * D_MODEL + (c0 + n * 16)] = f2bf(acc[m][n][j] * sc);
  }
}

// ---------------------------------------------------------------- output projection C = A*B^T, f32 out
__global__ __launch_bounds__(256) void gemm_out(const u16* __restrict__ A,
                                                const u16* __restrict__ B,
                                                float* __restrict__ C) {
  __shared__ u16 As[128 * 64];
  __shared__ u16 Bs[128 * 64];
  const int t = threadIdx.x, lane = t & 63, wave = t >> 6;
  const int wr = wave >> 1, wc = wave & 1;
  const int frow = lane & 15, fk = (lane >> 4) * 8;
  const int bM = blockIdx.y * 128, bN = blockIdx.x * 128;

  f32x4 acc[4][4] = {};

  for (int k0 = 0; k0 < D_MODEL; k0 += 64) {
    __syncthreads();
#pragma unroll
    for (int p = 0; p < 4; ++p) {
      int chunk = p * 256 + t;
      int r = chunk >> 3, cc = chunk & 7;
      GLD16(A + (size_t)(bM + r) * D_MODEL + k0 + cc * 8, As + (size_t)(p * 256 + (t & ~63)) * 8);
      GLD16(B + (size_t)(bN + r) * D_MODEL + k0 + cc * 8, Bs + (size_t)(p * 256 + (t & ~63)) * 8);
    }
    __syncthreads();

    bf16x8 a[2][4], b[2][4];
#pragma unroll
    for (int kk = 0; kk < 2; ++kk) {
#pragma unroll
      for (int m = 0; m < 4; ++m)
        a[kk][m] = *(const bf16x8*)&As[(wr * 64 + m * 16 + frow) * 64 + kk * 32 + fk];
#pragma unroll
      for (int n = 0; n < 4; ++n)
        b[kk][n] = *(const bf16x8*)&Bs[(wc * 64 + n * 16 + frow) * 64 + kk * 32 + fk];
    }
#pragma unroll
    for (int kk = 0; kk < 2; ++kk)
#pragma unroll
      for (int m = 0; m < 4; ++m)
#pragma unroll
        for (int n = 0; n < 4; ++n)
          acc[m][n] = __builtin_amdgcn_mfma_f32_16x16x32_bf16(a[kk][m], b[kk][n], acc[m][n], 0, 0, 0);
  }

  const int r0 = bM + wr * 64 + (lane >> 4) * 4;
  const int c0 = bN + wc * 64 + (lane & 15);
#pragma unroll
  for (int m = 0; m < 4; ++m)
#pragma unroll
    for (int n = 0; n < 4; ++n)
#pragma unroll
      for (int j = 0; j < 4; ++j)
        C[(size_t)(r0 + m * 16 + j) * D_MODEL + (c0 + n * 16)] = acc[m][n][j];
}

// ---------------------------------------------------------------- flash attention (causal)
// R3-proven structure: 4 waves x 32 q-rows per block, KV tile 64 double-buffered via
// global_load_lds; swapped QK^T; per-m P pipeline through 16x64 wave-private LDS; defer-max.
// Deltas vs R3: exp2-domain softmax; balanced qi->qtile map so each CU's co-resident
// quad {c,c+4,c+8,c+12} sums to 30 tile-indices (uniform 68 iters/CU, grid = residency).
__global__ __launch_bounds__(256) void attn_fwd(const u16* __restrict__ Q,
                                                const u16* __restrict__ K,
                                                const u16* __restrict__ Vt,
                                                u16* __restrict__ O) {
  __shared__ u16 Kl[2][64 * 64];   // 16 KB (dbuf)
  __shared__ u16 Vl[2][64 * 64];   // 16 KB (dbuf)
  __shared__ u16 Pl[4][16 * 64];   // 8 KB -> 40 KB total, 4 blocks/CU

  const int t = threadIdx.x, lane = t & 63, wave = t >> 6;
  const int c = lane & 15, g = lane >> 4;
  const int bh = blockIdx.x & 63;           // bh fastest: same-KV blocks spread over XCDs
  const int qi = blockIdx.x >> 6;           // 0..15
  // balanced permutation: {c,c+4,c+8,c+12} sums to 30 for c=0..3
  const int qmap[16] = {15, 14, 13, 12, 0, 1, 2, 3, 11, 10, 9, 8, 4, 5, 6, 7};
  const int qtile = qmap[qi];
  const int q0 = qtile * 128;
  const size_t rowbase = (size_t)(bh >> 4) * SEQ;
  const int hcol = (bh & 15) * DKH;
  const int qw = q0 + wave * 32;
  u16* pw = Pl[wave];
  const int nit = qtile * 2 + 2;

  auto stage = [&](int buf, int kv0) {
#pragma unroll
    for (int p = 0; p < 2; ++p) {
      int chunk = p * 256 + t;
      int r = chunk >> 3, cc = chunk & 7;
      int cs = cc ^ (r & 7);  // pre-swizzled global source; LDS linear
      GLD16(K + (rowbase + kv0 + r) * D_MODEL + hcol + cs * 8,
            &Kl[buf][(size_t)(p * 256 + (t & ~63)) * 8]);
      GLD16(Vt + ((size_t)bh * DKH + r) * SEQ + kv0 + cs * 8,
            &Vl[buf][(size_t)(p * 256 + (t & ~63)) * 8]);
    }
  };

  stage(0, 0);

  bf16x8 qf[2][2];
#pragma unroll
  for (int m = 0; m < 2; ++m)
#pragma unroll
    for (int kk = 0; kk < 2; ++kk)
      qf[m][kk] = *(const bf16x8*)&Q[(rowbase + qw + m * 16 + c) * D_MODEL + hcol + kk * 32 + g * 8];

  f32x4 ot[4][2] = {};              // O^T[d_local][q]
  float mstate[2] = {-__builtin_inff(), -__builtin_inff()};
  float lstate[2] = {0.f, 0.f};

  __syncthreads();
  int cur = 0;
  for (int it = 0; it < nit; ++it) {
    const int kv0 = it * 64;
    if (it + 1 < nit) stage(cur ^ 1, kv0 + 64);

    if (kv0 <= qw + 31) {  // wave-uniform causal participation
      // ---- S^T = K Q^T (exp2-domain scores)
      bf16x8 kf[4][2];
#pragma unroll
      for (int n = 0; n < 4; ++n)
#pragma unroll
        for (int kk = 0; kk < 2; ++kk)
          kf[n][kk] = *(const bf16x8*)&Kl[cur][(n * 16 + c) * 64 + (((g + 4 * kk) ^ (c & 7)) * 8)];
      f32x4 s[4][2] = {};
      __builtin_amdgcn_s_setprio(1);
#pragma unroll
      for (int kk = 0; kk < 2; ++kk)
#pragma unroll
        for (int n = 0; n < 4; ++n)
#pragma unroll
          for (int m = 0; m < 2; ++m)
            s[n][m] = __builtin_amdgcn_mfma_f32_16x16x32_bf16(kf[n][kk], qf[m][kk], s[n][m], 0, 0, 0);
      __builtin_amdgcn_s_setprio(0);

      // V^T fragments early: ds_read latency hides under softmax VALU
      bf16x8 vf[4][2];
#pragma unroll
      for (int d = 0; d < 4; ++d)
#pragma unroll
        for (int kk = 0; kk < 2; ++kk)
          vf[d][kk] = *(const bf16x8*)&Vl[cur][(d * 16 + c) * 64 + (((g + 4 * kk) ^ (c & 7)) * 8)];

      const bool need_mask = (kv0 + 63 > qw);
#pragma unroll
      for (int m = 0; m < 2; ++m) {
        const int qg = qw + m * 16 + c;
        if (need_mask) {
#pragma unroll
          for (int n = 0; n < 4; ++n)
#pragma unroll
            for (int j2 = 0; j2 < 4; ++j2)
              if (kv0 + n * 16 + g * 4 + j2 > qg) s[n][m][j2] = -__builtin_inff();
        }
        float pmax = fmaxf(fmaxf(s[0][m][0], s[0][m][1]), fmaxf(s[0][m][2], s[0][m][3]));
#pragma unroll
        for (int n = 1; n < 4; ++n)
          pmax = fmaxf(pmax, fmaxf(fmaxf(s[n][m][0], s[n][m][1]), fmaxf(s[n][m][2], s[n][m][3])));
        pmax = fmaxf(pmax, __shfl_xor(pmax, 16));
        pmax = fmaxf(pmax, __shfl_xor(pmax, 32));
        // defer-max (T13), log2 domain: P bounded by 2^11.54 = e^8
        if (__any(pmax > mstate[m] + 11.5416f)) {
          float mnew = fmaxf(mstate[m], pmax);
          float al = exp2f(mstate[m] - mnew);  // first tile: exp2(-inf)=0
          mstate[m] = mnew;
          lstate[m] *= al;
#pragma unroll
          for (int d = 0; d < 4; ++d)
#pragma unroll
            for (int j2 = 0; j2 < 4; ++j2) ot[d][m][j2] *= al;
        }
        const float mm = mstate[m];
        float lsum = 0.f;
#pragma unroll
        for (int n = 0; n < 4; ++n) {
          float p0 = exp2f(s[n][m][0] - mm);
          float p1 = exp2f(s[n][m][1] - mm);
          float p2 = exp2f(s[n][m][2] - mm);
          float p3 = exp2f(s[n][m][3] - mm);
          lsum += (p0 + p1) + (p2 + p3);
          // P[q=c][k=n*16+g*4+j], 16B-chunk XOR swizzle by row&7
          *(ushort4*)&pw[c * 64 + (((n * 2 + (g >> 1)) ^ (c & 7)) * 8) + (g & 1) * 4] =
              make_ushort4(f2bf(p0), f2bf(p1), f2bf(p2), f2bf(p3));
        }
        lsum += __shfl_xor(lsum, 16);
        lsum += __shfl_xor(lsum, 32);
        lstate[m] += lsum;

        // ---- O^T[.,m] += V^T P^T (wave-private LDS roundtrip; in-order DS ops, no barrier)
        bf16x8 pf[2];
#pragma unroll
        for (int kk = 0; kk < 2; ++kk)
          pf[kk] = *(const bf16x8*)&pw[c * 64 + (((g + 4 * kk) ^ (c & 7)) * 8)];
        __builtin_amdgcn_s_setprio(1);
#pragma unroll
        for (int kk = 0; kk < 2; ++kk)
#pragma unroll
          for (int d = 0; d < 4; ++d)
            ot[d][m] = __builtin_amdgcn_mfma_f32_16x16x32_bf16(vf[d][kk], pf[kk], ot[d][m], 0, 0, 0);
        __builtin_amdgcn_s_setprio(0);
      }
    }
    __syncthreads();
    cur ^= 1;
  }

  // ---- epilogue: O[q][d] = O^T/l
#pragma unroll
  for (int m = 0; m < 2; ++m) {
    float inv = 1.0f / lstate[m];
#pragma unroll
    for (int d = 0; d < 4; ++d) {
      ushort4 o4 = make_ushort4(f2bf(ot[d][m][0] * inv), f2bf(ot[d][m][1] * inv),
                                f2bf(ot[d][m][2] * inv), f2bf(ot[d][m][3] * inv));
      *(ushort4*)&O[(rowbase + qw + m * 16 + c) * D_MODEL + hcol + d * 16 + g * 4] = o4;
    }
  }
}

// ---------------------------------------------------------------- launch
extern "C" void kernel_launch(void* const* d_in, const int* in_sizes, int n_in,
                              void* d_out, int out_size, void* d_ws, size_t ws_size,
                              hipStream_t stream) {
  const float* x  = (const float*)d_in[0];
  const float* Wq = (const float*)d_in[1];
  const float* Wk = (const float*)d_in[2];
  const float* Wv = (const float*)d_in[3];
  const float* Wo = (const float*)d_in[4];
  float* out = (float*)d_out;

  u16* ws  = (u16*)d_ws;
  u16* xb  = ws;
  u16* wqb = xb + (size_t)NTOK * D_MODEL;
  u16* wkb = wqb + (size_t)D_MODEL * D_MODEL;
  u16* wvb = wkb + (size_t)D_MODEL * D_MODEL;
  u16* wob = wvb + (size_t)D_MODEL * D_MODEL;
  u16* Qb  = wob + (size_t)D_MODEL * D_MODEL;
  u16* Kb  = Qb + (size_t)NTOK * D_MODEL;
  u16* Vb  = Kb + (size_t)NTOK * D_MODEL;   // per-head V^T [B*H*64][SEQ]
  u16* Ob  = xb;  // reuse x's bf16 buffer after projections

  cvt_all<<<2048, 256, 0, stream>>>(x, Wq, Wk, Wv, Wo, xb, wqb, wkb, wvb, wob);

  gemm_qkv<<<dim3(D_MODEL / 128, NTOK / 128, 3), 256, 0, stream>>>(xb, wqb, wkb, wvb, Qb, Kb, Vb);

  attn_fwd<<<dim3(16 * 64), 256, 0, stream>>>(Qb, Kb, Vb, Ob);

  gemm_out<<<dim3(D_MODEL / 128, NTOK / 128), 256, 0, stream>>>(Ob, wob, out);
}

// Round 9
// 211.102 us; speedup vs baseline: 1.2039x; 1.1101x over previous
//
#include <hip/hip_runtime.h>
#include <hip/hip_bf16.h>
#include <stdint.h>

// Problem constants
#define D_MODEL 1024
#define NHEADS  16
#define DKH     64
#define BATCH   4
#define SEQ     2048
#define NTOK    (BATCH * SEQ)   // 8192

typedef unsigned short u16;
using bf16x8 = __attribute__((ext_vector_type(8))) short;   // 8 bf16 = 4 VGPR (MFMA A/B frag)
using f32x4  = __attribute__((ext_vector_type(4))) float;   // MFMA C/D frag

// async global->LDS, 16B per lane; LDS dest is wave-uniform base (+lane*16 by HW)
#define GLD16(g, l)                                                            \
  __builtin_amdgcn_global_load_lds(                                            \
      (const __attribute__((address_space(1))) void*)(g),                      \
      (__attribute__((address_space(3))) void*)(l), 16, 0, 0)

__device__ inline u16 f2bf(float f) {
  __hip_bfloat16 h = __float2bfloat16(f);
  return __builtin_bit_cast(u16, h);
}

// single v_exp_f32 via intrinsic (compiler inserts TRANS-op hazard nops)
__device__ inline float fexp2(float x) { return __builtin_amdgcn_exp2f(x); }

// ---------------------------------------------------------------- fused converts
__global__ __launch_bounds__(256) void cvt_all(const float* __restrict__ x,
                                               const float* __restrict__ wq,
                                               const float* __restrict__ wk,
                                               const float* __restrict__ wv,
                                               const float* __restrict__ wo,
                                               u16* xb, u16* wqb, u16* wkb, u16* wvb, u16* wob) {
  const int XC = NTOK * D_MODEL / 4;      // 2097152
  const int WC = D_MODEL * D_MODEL / 4;   // 262144
  const int total = XC + 4 * WC;
  for (int i = blockIdx.x * 256 + threadIdx.x; i < total; i += gridDim.x * 256) {
    const float4* s; ushort4* d; int j;
    if (i < XC)              { s = (const float4*)x;  d = (ushort4*)xb;  j = i; }
    else if (i < XC + WC)    { s = (const float4*)wq; d = (ushort4*)wqb; j = i - XC; }
    else if (i < XC + 2*WC)  { s = (const float4*)wk; d = (ushort4*)wkb; j = i - XC - WC; }
    else if (i < XC + 3*WC)  { s = (const float4*)wv; d = (ushort4*)wvb; j = i - XC - 2*WC; }
    else                     { s = (const float4*)wo; d = (ushort4*)wob; j = i - XC - 3*WC; }
    float4 v = s[j];
    d[j] = make_ushort4(f2bf(v.x), f2bf(v.y), f2bf(v.z), f2bf(v.w));
  }
}

// ---------------------------------------------------------------- fused QKV projection
// A [NTOK,D] bf16; Bq/Bk/Bv [D,D] bf16 (nn.Linear layout, C = A*B^T).
// z=0: Q out, scaled 0.125*log2(e) (exp2-domain softmax). z=1: K. z=2: V transposed per-head.
__global__ __launch_bounds__(256) void gemm_qkv(const u16* __restrict__ A,
                                                const u16* __restrict__ Bq,
                                                const u16* __restrict__ Bk,
                                                const u16* __restrict__ Bv,
                                                u16* __restrict__ Qo,
                                                u16* __restrict__ Ko,
                                                u16* __restrict__ Vo) {
  __shared__ u16 As[128 * 64];
  __shared__ u16 Bs[128 * 64];
  const int z = blockIdx.z;
  const u16* __restrict__ Bp = z == 0 ? Bq : (z == 1 ? Bk : Bv);
  const int t = threadIdx.x, lane = t & 63, wave = t >> 6;
  const int wr = wave >> 1, wc = wave & 1;
  const int frow = lane & 15, fk = (lane >> 4) * 8;
  const int bM = blockIdx.y * 128, bN = blockIdx.x * 128;

  f32x4 acc[4][4] = {};

  for (int k0 = 0; k0 < D_MODEL; k0 += 64) {
    __syncthreads();
#pragma unroll
    for (int p = 0; p < 4; ++p) {
      int chunk = p * 256 + t;
      int r = chunk >> 3, cc = chunk & 7;
      GLD16(A + (size_t)(bM + r) * D_MODEL + k0 + cc * 8, As + (size_t)(p * 256 + (t & ~63)) * 8);
      GLD16(Bp + (size_t)(bN + r) * D_MODEL + k0 + cc * 8, Bs + (size_t)(p * 256 + (t & ~63)) * 8);
    }
    __syncthreads();

    bf16x8 a[2][4], b[2][4];
#pragma unroll
    for (int kk = 0; kk < 2; ++kk) {
#pragma unroll
      for (int m = 0; m < 4; ++m)
        a[kk][m] = *(const bf16x8*)&As[(wr * 64 + m * 16 + frow) * 64 + kk * 32 + fk];
#pragma unroll
      for (int n = 0; n < 4; ++n)
        b[kk][n] = *(const bf16x8*)&Bs[(wc * 64 + n * 16 + frow) * 64 + kk * 32 + fk];
    }
#pragma unroll
    for (int kk = 0; kk < 2; ++kk)
#pragma unroll
      for (int m = 0; m < 4; ++m)
#pragma unroll
        for (int n = 0; n < 4; ++n)
          acc[m][n] = __builtin_amdgcn_mfma_f32_16x16x32_bf16(a[kk][m], b[kk][n], acc[m][n], 0, 0, 0);
  }

  const int r0 = bM + wr * 64 + (lane >> 4) * 4;
  const int c0 = bN + wc * 64 + (lane & 15);
  if (z == 2) {
#pragma unroll
    for (int m = 0; m < 4; ++m)
#pragma unroll
      for (int n = 0; n < 4; ++n) {
        int r = r0 + m * 16;   // token (4-aligned, j stays in one batch)
        int cc = c0 + n * 16;  // d_model col
        size_t off = ((size_t)(r >> 11) * D_MODEL + cc) * SEQ + (r & (SEQ - 1));
        *(ushort4*)(Vo + off) = make_ushort4(f2bf(acc[m][n][0]), f2bf(acc[m][n][1]),
                                             f2bf(acc[m][n][2]), f2bf(acc[m][n][3]));
      }
  } else {
    u16* C = z ? Ko : Qo;
    const float sc = z ? 1.0f : 0.18033688f;  // (1/8)*log2(e): softmax in exp2 domain
#pragma unroll
    for (int m = 0; m < 4; ++m)
#pragma unroll
      for (int n = 0; n < 4; ++n)
#pragma unroll
        for (int j = 0; j < 4; ++j)
          C[(size_t)(r0 + m * 16 + j) * D_MODEL + (c0 + n * 16)] = f2bf(acc[m][n][j] * sc);
  }
}

// ---------------------------------------------------------------- output projection C = A*B^T, f32 out
__global__ __launch_bounds__(256) void gemm_out(const u16* __restrict__ A,
                                                const u16* __restrict__ B,
                                                float* __restrict__ C) {
  __shared__ u16 As[128 * 64];
  __shared__ u16 Bs[128 * 64];
  const int t = threadIdx.x, lane = t & 63, wave = t >> 6;
  const int wr = wave >> 1, wc = wave & 1;
  const int frow = lane & 15, fk = (lane >> 4) * 8;
  const int bM = blockIdx.y * 128, bN = blockIdx.x * 128;

  f32x4 acc[4][4] = {};

  for (int k0 = 0; k0 < D_MODEL; k0 += 64) {
    __syncthreads();
#pragma unroll
    for (int p = 0; p < 4; ++p) {
      int chunk = p * 256 + t;
      int r = chunk >> 3, cc = chunk & 7;
      GLD16(A + (size_t)(bM + r) * D_MODEL + k0 + cc * 8, As + (size_t)(p * 256 + (t & ~63)) * 8);
      GLD16(B + (size_t)(bN + r) * D_MODEL + k0 + cc * 8, Bs + (size_t)(p * 256 + (t & ~63)) * 8);
    }
    __syncthreads();

    bf16x8 a[2][4], b[2][4];
#pragma unroll
    for (int kk = 0; kk < 2; ++kk) {
#pragma unroll
      for (int m = 0; m < 4; ++m)
        a[kk][m] = *(const bf16x8*)&As[(wr * 64 + m * 16 + frow) * 64 + kk * 32 + fk];
#pragma unroll
      for (int n = 0; n < 4; ++n)
        b[kk][n] = *(const bf16x8*)&Bs[(wc * 64 + n * 16 + frow) * 64 + kk * 32 + fk];
    }
#pragma unroll
    for (int kk = 0; kk < 2; ++kk)
#pragma unroll
      for (int m = 0; m < 4; ++m)
#pragma unroll
        for (int n = 0; n < 4; ++n)
          acc[m][n] = __builtin_amdgcn_mfma_f32_16x16x32_bf16(a[kk][m], b[kk][n], acc[m][n], 0, 0, 0);
  }

  const int r0 = bM + wr * 64 + (lane >> 4) * 4;
  const int c0 = bN + wc * 64 + (lane & 15);
#pragma unroll
  for (int m = 0; m < 4; ++m)
#pragma unroll
    for (int n = 0; n < 4; ++n)
#pragma unroll
      for (int j = 0; j < 4; ++j)
        C[(size_t)(r0 + m * 16 + j) * D_MODEL + (c0 + n * 16)] = acc[m][n][j];
}

// ---------------------------------------------------------------- flash attention (causal)
// Q (pre-scaled 0.125*log2e), K: bf16 [NTOK, D_MODEL]; Vt: bf16 [B*H*64][SEQ];
// O: bf16 [NTOK, D_MODEL].
// UNIFORM BLOCKS: each block sequentially processes two 64-row half-tiles of one (b,h):
// (qtile=15-p, h=0) then (qtile=p, h=1) -> exactly 33 KV-iters per block, identical
// work for all 1024 blocks. 4 waves x 16 q-rows per item. dbuf global_load_lds staging,
// swapped QK^T, wave-private P LDS roundtrip, defer-max, exp2-domain softmax.
// MASK CONDITION: tile needs masking iff tile max-k exceeds wave MIN q (kv0+63 > qw16).
// R7/R8 used max-q (qw16+15) -> future-key leak on waves 1-3 of each half-tile (absmax .09).
__global__ __launch_bounds__(256) void attn_fwd(const u16* __restrict__ Q,
                                                const u16* __restrict__ K,
                                                const u16* __restrict__ Vt,
                                                u16* __restrict__ O) {
  __shared__ u16 Kl[2][64 * 64];   // 16 KB (dbuf)
  __shared__ u16 Vl[2][64 * 64];   // 16 KB (dbuf)
  __shared__ u16 Pl[4][16 * 64];   // 8 KB -> 40 KB total, 4 blocks/CU

  const int t = threadIdx.x, lane = t & 63, wave = t >> 6;
  const int c = lane & 15, g = lane >> 4;
  const int bh = blockIdx.x & 63;
  const int p = blockIdx.x >> 6;            // 0..15 pair index
  const size_t rowbase = (size_t)(bh >> 4) * SEQ;
  const int hcol = (bh & 15) * DKH;
  const size_t vbase = (size_t)bh * DKH;
  u16* pw = Pl[wave];

  auto stage = [&](int buf, int kv0) {
#pragma unroll
    for (int pp = 0; pp < 2; ++pp) {
      int chunk = pp * 256 + t;
      int r = chunk >> 3, cc = chunk & 7;
      int cs = cc ^ (r & 7);  // pre-swizzled global source; LDS linear
      GLD16(K + (rowbase + kv0 + r) * D_MODEL + hcol + cs * 8,
            &Kl[buf][(size_t)(pp * 256 + (t & ~63)) * 8]);
      GLD16(Vt + (vbase + r) * SEQ + kv0 + cs * 8,
            &Vl[buf][(size_t)(pp * 256 + (t & ~63)) * 8]);
    }
  };

#pragma unroll 1
  for (int item = 0; item < 2; ++item) {
    const int qt = item ? p : 15 - p;       // half-tile pair: iters sum to 33 exactly
    const int q0 = qt * 128 + item * 64;    // item's 64-row base
    const int qw16 = q0 + wave * 16;        // this wave's 16 q-rows
    const int nit = (q0 >> 6) + 1;          // KV tiles (covers causal prefix exactly)

    stage(0, 0);

    bf16x8 qf[2];
#pragma unroll
    for (int kk = 0; kk < 2; ++kk)
      qf[kk] = *(const bf16x8*)&Q[(rowbase + qw16 + c) * D_MODEL + hcol + kk * 32 + g * 8];

    f32x4 ot[4] = {};                 // O^T[d_local], cols q=c
    float mstate = -__builtin_inff();
    float lstate = 0.f;

    __syncthreads();                  // staging of buf0 complete (vmcnt drained at barrier)
    int cur = 0;
    for (int it = 0; it < nit; ++it) {
      const int kv0 = it * 64;
      if (it + 1 < nit) stage(cur ^ 1, kv0 + 64);

      // ---- S^T = K Q^T (exp2-domain scores); all waves participate every iter
      bf16x8 kf[4][2];
#pragma unroll
      for (int n = 0; n < 4; ++n)
#pragma unroll
        for (int kk = 0; kk < 2; ++kk)
          kf[n][kk] = *(const bf16x8*)&Kl[cur][(n * 16 + c) * 64 + (((g + 4 * kk) ^ (c & 7)) * 8)];
      f32x4 s[4] = {};
      __builtin_amdgcn_s_setprio(1);
#pragma unroll
      for (int kk = 0; kk < 2; ++kk)
#pragma unroll
        for (int n = 0; n < 4; ++n)
          s[n] = __builtin_amdgcn_mfma_f32_16x16x32_bf16(kf[n][kk], qf[kk], s[n], 0, 0, 0);
      __builtin_amdgcn_s_setprio(0);

      // V^T fragments early: ds_read latency hides under softmax VALU
      bf16x8 vf[4][2];
#pragma unroll
      for (int d = 0; d < 4; ++d)
#pragma unroll
        for (int kk = 0; kk < 2; ++kk)
          vf[d][kk] = *(const bf16x8*)&Vl[cur][(d * 16 + c) * 64 + (((g + 4 * kk) ^ (c & 7)) * 8)];

      const int qg = qw16 + c;
      if (kv0 + 63 > qw16) {          // mask iff tile max-k > wave MIN q (R8 bugfix)
#pragma unroll
        for (int n = 0; n < 4; ++n)
#pragma unroll
          for (int j2 = 0; j2 < 4; ++j2)
            if (kv0 + n * 16 + g * 4 + j2 > qg) s[n][j2] = -__builtin_inff();
      }
      float pmax = fmaxf(fmaxf(s[0][0], s[0][1]), fmaxf(s[0][2], s[0][3]));
#pragma unroll
      for (int n = 1; n < 4; ++n)
        pmax = fmaxf(pmax, fmaxf(fmaxf(s[n][0], s[n][1]), fmaxf(s[n][2], s[n][3])));
      pmax = fmaxf(pmax, __shfl_xor(pmax, 16));
      pmax = fmaxf(pmax, __shfl_xor(pmax, 32));
      // defer-max (T13), log2 domain: P bounded by 2^11.54 = e^8
      if (__any(pmax > mstate + 11.5416f)) {
        float mnew = fmaxf(mstate, pmax);
        float al = fexp2(mstate - mnew);  // first tile: exp2(-inf)=0
        mstate = mnew;
        lstate *= al;
#pragma unroll
        for (int d = 0; d < 4; ++d)
#pragma unroll
          for (int j2 = 0; j2 < 4; ++j2) ot[d][j2] *= al;
      }
      const float mm = mstate;
      float lsum = 0.f;
#pragma unroll
      for (int n = 0; n < 4; ++n) {
        float p0 = fexp2(s[n][0] - mm);
        float p1 = fexp2(s[n][1] - mm);
        float p2 = fexp2(s[n][2] - mm);
        float p3 = fexp2(s[n][3] - mm);
        lsum += (p0 + p1) + (p2 + p3);
        // P[q=c][k=n*16+g*4+j], 16B-chunk XOR swizzle by row&7
        *(ushort4*)&pw[c * 64 + (((n * 2 + (g >> 1)) ^ (c & 7)) * 8) + (g & 1) * 4] =
            make_ushort4(f2bf(p0), f2bf(p1), f2bf(p2), f2bf(p3));
      }
      lsum += __shfl_xor(lsum, 16);
      lsum += __shfl_xor(lsum, 32);
      lstate += lsum;

      // ---- O^T += V^T P^T (wave-private LDS roundtrip; in-order DS ops, no barrier)
      bf16x8 pf[2];
#pragma unroll
      for (int kk = 0; kk < 2; ++kk)
        pf[kk] = *(const bf16x8*)&pw[c * 64 + (((g + 4 * kk) ^ (c & 7)) * 8)];
      __builtin_amdgcn_s_setprio(1);
#pragma unroll
      for (int kk = 0; kk < 2; ++kk)
#pragma unroll
        for (int d = 0; d < 4; ++d)
          ot[d] = __builtin_amdgcn_mfma_f32_16x16x32_bf16(vf[d][kk], pf[kk], ot[d], 0, 0, 0);
      __builtin_amdgcn_s_setprio(0);

      __syncthreads();
      cur ^= 1;
    }

    // ---- epilogue: O[q][d] = O^T/l (16 rows); LDS untouched -> safe before next item
    float inv = 1.0f / lstate;
#pragma unroll
    for (int d = 0; d < 4; ++d) {
      ushort4 o4 = make_ushort4(f2bf(ot[d][0] * inv), f2bf(ot[d][1] * inv),
                                f2bf(ot[d][2] * inv), f2bf(ot[d][3] * inv));
      *(ushort4*)&O[(rowbase + qw16 + c) * D_MODEL + hcol + d * 16 + g * 4] = o4;
    }
  }
}

// ---------------------------------------------------------------- launch
extern "C" void kernel_launch(void* const* d_in, const int* in_sizes, int n_in,
                              void* d_out, int out_size, void* d_ws, size_t ws_size,
                              hipStream_t stream) {
  const float* x  = (const float*)d_in[0];
  const float* Wq = (const float*)d_in[1];
  const float* Wk = (const float*)d_in[2];
  const float* Wv = (const float*)d_in[3];
  const float* Wo = (const float*)d_in[4];
  float* out = (float*)d_out;

  u16* ws  = (u16*)d_ws;
  u16* xb  = ws;
  u16* wqb = xb + (size_t)NTOK * D_MODEL;
  u16* wkb = wqb + (size_t)D_MODEL * D_MODEL;
  u16* wvb = wkb + (size_t)D_MODEL * D_MODEL;
  u16* wob = wvb + (size_t)D_MODEL * D_MODEL;
  u16* Qb  = wob + (size_t)D_MODEL * D_MODEL;
  u16* Kb  = Qb + (size_t)NTOK * D_MODEL;
  u16* Vb  = Kb + (size_t)NTOK * D_MODEL;   // per-head V^T [B*H*64][SEQ]
  u16* Ob  = xb;  // reuse x's bf16 buffer after projections

  cvt_all<<<2048, 256, 0, stream>>>(x, Wq, Wk, Wv, Wo, xb, wqb, wkb, wvb, wob);

  gemm_qkv<<<dim3(D_MODEL / 128, NTOK / 128, 3), 256, 0, stream>>>(xb, wqb, wkb, wvb, Qb, Kb, Vb);

  attn_fwd<<<dim3(16 * 64), 256, 0, stream>>>(Qb, Kb, Vb, Ob);

  gemm_out<<<dim3(D_MODEL / 128, NTOK / 128), 256, 0, stream>>>(Ob, wob, out);
}

// Round 10
// 189.587 us; speedup vs baseline: 1.3405x; 1.1135x over previous
//
#include <hip/hip_runtime.h>
#include <hip/hip_bf16.h>
#include <stdint.h>

// Problem constants
#define D_MODEL 1024
#define NHEADS  16
#define DKH     64
#define BATCH   4
#define SEQ     2048
#define NTOK    (BATCH * SEQ)   // 8192

typedef unsigned short u16;
using bf16x8 = __attribute__((ext_vector_type(8))) short;   // 8 bf16 = 4 VGPR (MFMA A/B frag)
using f32x4  = __attribute__((ext_vector_type(4))) float;   // 16x16 MFMA C/D frag
using f32x16 = __attribute__((ext_vector_type(16))) float;  // 32x32 MFMA C/D frag
using u32x2  = __attribute__((ext_vector_type(2))) unsigned int;

// async global->LDS, 16B per lane; LDS dest is wave-uniform base (+lane*16 by HW)
#define GLD16(g, l)                                                            \
  __builtin_amdgcn_global_load_lds(                                            \
      (const __attribute__((address_space(1))) void*)(g),                      \
      (__attribute__((address_space(3))) void*)(l), 16, 0, 0)

__device__ inline u16 f2bf(float f) {
  __hip_bfloat16 h = __float2bfloat16(f);
  return __builtin_bit_cast(u16, h);
}

// single v_exp_f32 via intrinsic (compiler inserts TRANS-op hazard nops)
__device__ inline float fexp2(float x) { return __builtin_amdgcn_exp2f(x); }

// packed f32x2 -> bf16x2 (RNE in HW); plain VALU op, T12 recipe (m214v22)
__device__ inline unsigned cvtpk(float lo, float hi) {
  unsigned r;
  asm("v_cvt_pk_bf16_f32 %0, %1, %2" : "=v"(r) : "v"(lo), "v"(hi));
  return r;
}

// Build PV B-frag for one K=16 window from 8 in-register P values (T12):
// lane(q=l&31,hi) holds P[k=crow(r,hi)][q], crow=(r&3)+8*(r>>2)+4*hi.
// B-frag needs P[kwin+hi*8+i][q]. 4 cvt_pk + 2 permlane32_swap per window:
//   word0=swap(cvt(pB,pB+1),cvt(pB+4,pB+5)).x  word2=.y
//   word1=swap(cvt(pB+2,pB+3),cvt(pB+6,pB+7)).x word3=.y
template <int B>
__device__ inline bf16x8 make_pfrag(const f32x16& sv) {
  unsigned x1 = cvtpk(sv[B + 0], sv[B + 1]);
  unsigned y1 = cvtpk(sv[B + 4], sv[B + 5]);
  unsigned x2 = cvtpk(sv[B + 2], sv[B + 3]);
  unsigned y2 = cvtpk(sv[B + 6], sv[B + 7]);
  u32x2 s1 = __builtin_amdgcn_permlane32_swap(x1, y1, false, false);
  u32x2 s2 = __builtin_amdgcn_permlane32_swap(x2, y2, false, false);
  union { unsigned u[4]; bf16x8 v; } r;
  r.u[0] = s1[0]; r.u[1] = s2[0]; r.u[2] = s1[1]; r.u[3] = s2[1];
  return r.v;
}

// ---------------------------------------------------------------- fused converts
__global__ __launch_bounds__(256) void cvt_all(const float* __restrict__ x,
                                               const float* __restrict__ wq,
                                               const float* __restrict__ wk,
                                               const float* __restrict__ wv,
                                               const float* __restrict__ wo,
                                               u16* xb, u16* wqb, u16* wkb, u16* wvb, u16* wob) {
  const int XC = NTOK * D_MODEL / 4;      // 2097152
  const int WC = D_MODEL * D_MODEL / 4;   // 262144
  const int total = XC + 4 * WC;
  for (int i = blockIdx.x * 256 + threadIdx.x; i < total; i += gridDim.x * 256) {
    const float4* s; ushort4* d; int j;
    if (i < XC)              { s = (const float4*)x;  d = (ushort4*)xb;  j = i; }
    else if (i < XC + WC)    { s = (const float4*)wq; d = (ushort4*)wqb; j = i - XC; }
    else if (i < XC + 2*WC)  { s = (const float4*)wk; d = (ushort4*)wkb; j = i - XC - WC; }
    else if (i < XC + 3*WC)  { s = (const float4*)wv; d = (ushort4*)wvb; j = i - XC - 2*WC; }
    else                     { s = (const float4*)wo; d = (ushort4*)wob; j = i - XC - 3*WC; }
    float4 v = s[j];
    d[j] = make_ushort4(f2bf(v.x), f2bf(v.y), f2bf(v.z), f2bf(v.w));
  }
}

// ---------------------------------------------------------------- fused QKV projection
// A [NTOK,D] bf16; Bq/Bk/Bv [D,D] bf16 (nn.Linear layout, C = A*B^T).
// z=0: Q out, scaled 0.125*log2(e) (exp2-domain softmax). z=1: K. z=2: V transposed per-head.
__global__ __launch_bounds__(256) void gemm_qkv(const u16* __restrict__ A,
                                                const u16* __restrict__ Bq,
                                                const u16* __restrict__ Bk,
                                                const u16* __restrict__ Bv,
                                                u16* __restrict__ Qo,
                                                u16* __restrict__ Ko,
                                                u16* __restrict__ Vo) {
  __shared__ u16 As[128 * 64];
  __shared__ u16 Bs[128 * 64];
  const int z = blockIdx.z;
  const u16* __restrict__ Bp = z == 0 ? Bq : (z == 1 ? Bk : Bv);
  const int t = threadIdx.x, lane = t & 63, wave = t >> 6;
  const int wr = wave >> 1, wc = wave & 1;
  const int frow = lane & 15, fk = (lane >> 4) * 8;
  const int bM = blockIdx.y * 128, bN = blockIdx.x * 128;

  f32x4 acc[4][4] = {};

  for (int k0 = 0; k0 < D_MODEL; k0 += 64) {
    __syncthreads();
#pragma unroll
    for (int p = 0; p < 4; ++p) {
      int chunk = p * 256 + t;
      int r = chunk >> 3, cc = chunk & 7;
      GLD16(A + (size_t)(bM + r) * D_MODEL + k0 + cc * 8, As + (size_t)(p * 256 + (t & ~63)) * 8);
      GLD16(Bp + (size_t)(bN + r) * D_MODEL + k0 + cc * 8, Bs + (size_t)(p * 256 + (t & ~63)) * 8);
    }
    __syncthreads();

    bf16x8 a[2][4], b[2][4];
#pragma unroll
    for (int kk = 0; kk < 2; ++kk) {
#pragma unroll
      for (int m = 0; m < 4; ++m)
        a[kk][m] = *(const bf16x8*)&As[(wr * 64 + m * 16 + frow) * 64 + kk * 32 + fk];
#pragma unroll
      for (int n = 0; n < 4; ++n)
        b[kk][n] = *(const bf16x8*)&Bs[(wc * 64 + n * 16 + frow) * 64 + kk * 32 + fk];
    }
#pragma unroll
    for (int kk = 0; kk < 2; ++kk)
#pragma unroll
      for (int m = 0; m < 4; ++m)
#pragma unroll
        for (int n = 0; n < 4; ++n)
          acc[m][n] = __builtin_amdgcn_mfma_f32_16x16x32_bf16(a[kk][m], b[kk][n], acc[m][n], 0, 0, 0);
  }

  const int r0 = bM + wr * 64 + (lane >> 4) * 4;
  const int c0 = bN + wc * 64 + (lane & 15);
  if (z == 2) {
#pragma unroll
    for (int m = 0; m < 4; ++m)
#pragma unroll
      for (int n = 0; n < 4; ++n) {
        int r = r0 + m * 16;   // token (4-aligned, j stays in one batch)
        int cc = c0 + n * 16;  // d_model col
        size_t off = ((size_t)(r >> 11) * D_MODEL + cc) * SEQ + (r & (SEQ - 1));
        *(ushort4*)(Vo + off) = make_ushort4(f2bf(acc[m][n][0]), f2bf(acc[m][n][1]),
                                             f2bf(acc[m][n][2]), f2bf(acc[m][n][3]));
      }
  } else {
    u16* C = z ? Ko : Qo;
    const float sc = z ? 1.0f : 0.18033688f;  // (1/8)*log2(e): softmax in exp2 domain
#pragma unroll
    for (int m = 0; m < 4; ++m)
#pragma unroll
      for (int n = 0; n < 4; ++n)
#pragma unroll
        for (int j = 0; j < 4; ++j)
          C[(size_t)(r0 + m * 16 + j) * D_MODEL + (c0 + n * 16)] = f2bf(acc[m][n][j] * sc);
  }
}

// ---------------------------------------------------------------- output projection C = A*B^T, f32 out
__global__ __launch_bounds__(256) void gemm_out(const u16* __restrict__ A,
                                                const u16* __restrict__ B,
                                                float* __restrict__ C) {
  __shared__ u16 As[128 * 64];
  __shared__ u16 Bs[128 * 64];
  const int t = threadIdx.x, lane = t & 63, wave = t >> 6;
  const int wr = wave >> 1, wc = wave & 1;
  const int frow = lane & 15, fk = (lane >> 4) * 8;
  const int bM = blockIdx.y * 128, bN = blockIdx.x * 128;

  f32x4 acc[4][4] = {};

  for (int k0 = 0; k0 < D_MODEL; k0 += 64) {
    __syncthreads();
#pragma unroll
    for (int p = 0; p < 4; ++p) {
      int chunk = p * 256 + t;
      int r = chunk >> 3, cc = chunk & 7;
      GLD16(A + (size_t)(bM + r) * D_MODEL + k0 + cc * 8, As + (size_t)(p * 256 + (t & ~63)) * 8);
      GLD16(B + (size_t)(bN + r) * D_MODEL + k0 + cc * 8, Bs + (size_t)(p * 256 + (t & ~63)) * 8);
    }
    __syncthreads();

    bf16x8 a[2][4], b[2][4];
#pragma unroll
    for (int kk = 0; kk < 2; ++kk) {
#pragma unroll
      for (int m = 0; m < 4; ++m)
        a[kk][m] = *(const bf16x8*)&As[(wr * 64 + m * 16 + frow) * 64 + kk * 32 + fk];
#pragma unroll
      for (int n = 0; n < 4; ++n)
        b[kk][n] = *(const bf16x8*)&Bs[(wc * 64 + n * 16 + frow) * 64 + kk * 32 + fk];
    }
#pragma unroll
    for (int kk = 0; kk < 2; ++kk)
#pragma unroll
      for (int m = 0; m < 4; ++m)
#pragma unroll
        for (int n = 0; n < 4; ++n)
          acc[m][n] = __builtin_amdgcn_mfma_f32_16x16x32_bf16(a[kk][m], b[kk][n], acc[m][n], 0, 0, 0);
  }

  const int r0 = bM + wr * 64 + (lane >> 4) * 4;
  const int c0 = bN + wc * 64 + (lane & 15);
#pragma unroll
  for (int m = 0; m < 4; ++m)
#pragma unroll
    for (int n = 0; n < 4; ++n)
#pragma unroll
      for (int j = 0; j < 4; ++j)
        C[(size_t)(r0 + m * 16 + j) * D_MODEL + (c0 + n * 16)] = acc[m][n][j];
}

// ---------------------------------------------------------------- flash attention (causal)
// 32x32-MFMA structure (m214-style): 4 waves x 32 q-rows = 128-row q-tile per block.
// Swapped QK^T: S^T=mfma32(K,Q) -> lane(q=l&31,hi) holds S[k=crow(r,hi)][q],
// crow=(r&3)+8*(r>>2)+4*hi. Softmax lane-local (31 ops + 1 shfl_xor(32)).
// P stays IN REGISTERS: PV B-frag via cvt_pk+permlane32_swap (T12). O^T=mfma32(Vt,P)
// keeps q=lane&31 so alpha/l rescale is lane-aligned. K/Vt staged via global_load_lds
// with source-chunk XOR swizzle, double-buffered. defer-max; exp2-domain softmax.
__global__ __launch_bounds__(256) void attn_fwd(const u16* __restrict__ Q,
                                                const u16* __restrict__ K,
                                                const u16* __restrict__ Vt,
                                                u16* __restrict__ O) {
  __shared__ u16 Kl[2][64 * 64];   // 16 KB (dbuf)
  __shared__ u16 Vl[2][64 * 64];   // 16 KB (dbuf) -> 32 KB total
  const int t = threadIdx.x, lane = t & 63, wave = t >> 6;
  const int q = lane & 31, hi = lane >> 5;
  const int bh = blockIdx.x & 63;           // bh fastest
  const int qtile = 15 - (blockIdx.x >> 6); // heavy-first (R3-proven)
  const int q0 = qtile * 128;
  const size_t rowbase = (size_t)(bh >> 4) * SEQ;
  const int hcol = (bh & 15) * DKH;
  const size_t vbase = (size_t)bh * DKH;
  const int qw = q0 + wave * 32;            // this wave's 32 q-rows
  const int nit = qtile * 2 + 2;

  auto stage = [&](int buf, int kv0) {
#pragma unroll
    for (int pp = 0; pp < 2; ++pp) {
      int chunk = pp * 256 + t;
      int r = chunk >> 3, cc = chunk & 7;
      int cs = cc ^ (r & 7);  // pre-swizzled global source; LDS linear
      GLD16(K + (rowbase + kv0 + r) * D_MODEL + hcol + cs * 8,
            &Kl[buf][(size_t)(pp * 256 + (t & ~63)) * 8]);
      GLD16(Vt + (vbase + r) * SEQ + kv0 + cs * 8,
            &Vl[buf][(size_t)(pp * 256 + (t & ~63)) * 8]);
    }
  };

  stage(0, 0);

  // Q B-frags: lane(q,hi) holds Q[qw+q][w*16 + hi*8 + i], w=0..3 (16 VGPR)
  bf16x8 qf[4];
#pragma unroll
  for (int w = 0; w < 4; ++w)
    qf[w] = *(const bf16x8*)&Q[(rowbase + qw + q) * D_MODEL + hcol + w * 16 + hi * 8];

  f32x16 ot0 = {}, ot1 = {};        // O^T: col q=lane&31, row d=crow(r,hi) (+32 for ot1)
  float mstate = -__builtin_inff();
  float lstate = 0.f;

  __syncthreads();
  int cur = 0;
  for (int it = 0; it < nit; ++it) {
    const int kv0 = it * 64;
    if (it + 1 < nit) stage(cur ^ 1, kv0 + 64);

    if (kv0 <= qw + 31) {  // wave-uniform causal participation
      // ---- S^T tiles: s0 = K[kv0..kv0+31] Q^T, s1 = K[kv0+32..63] Q^T
      f32x16 s0 = {}, s1 = {};
      __builtin_amdgcn_s_setprio(1);
#pragma unroll
      for (int w = 0; w < 4; ++w) {
        const int rk0 = q, rk1 = 32 + q;   // (32+q)&7 == q&7
        bf16x8 k0 = *(const bf16x8*)&Kl[cur][rk0 * 64 + (((2 * w + hi) ^ (rk0 & 7)) * 8)];
        bf16x8 k1 = *(const bf16x8*)&Kl[cur][rk1 * 64 + (((2 * w + hi) ^ (rk0 & 7)) * 8)];
        s0 = __builtin_amdgcn_mfma_f32_32x32x16_bf16(k0, qf[w], s0, 0, 0, 0);
        s1 = __builtin_amdgcn_mfma_f32_32x32x16_bf16(k1, qf[w], s1, 0, 0, 0);
      }
      __builtin_amdgcn_s_setprio(0);

      // ---- mask (diagonal tiles only): k = kv0 + {0,32} + crow(r,hi); q_g = qw+q
      const int qg = qw + q;
      if (kv0 + 63 > qw) {
#pragma unroll
        for (int r = 0; r < 16; ++r) {
          const int crow = (r & 3) + 8 * (r >> 2) + 4 * hi;
          if (kv0 + crow > qg) s0[r] = -__builtin_inff();
          if (kv0 + 32 + crow > qg) s1[r] = -__builtin_inff();
        }
      }

      // ---- lane-local max over 32 vals + 1 cross-half swap
      float pmax = fmaxf(s0[0], s0[1]);
#pragma unroll
      for (int r = 2; r < 16; ++r) pmax = fmaxf(pmax, s0[r]);
#pragma unroll
      for (int r = 0; r < 16; ++r) pmax = fmaxf(pmax, s1[r]);
      pmax = fmaxf(pmax, __shfl_xor(pmax, 32));

      // defer-max (T13), log2 domain: P bounded by 2^11.54 = e^8
      if (__any(pmax > mstate + 11.5416f)) {
        float mnew = fmaxf(mstate, pmax);
        float al = fexp2(mstate - mnew);  // first tile: exp2(-inf)=0
        mstate = mnew;
        lstate *= al;
#pragma unroll
        for (int r = 0; r < 16; ++r) { ot0[r] *= al; ot1[r] *= al; }
      }
      const float mm = mstate;

      // ---- exp (in place) + row-sum
      float lsum = 0.f;
#pragma unroll
      for (int r = 0; r < 16; ++r) { s0[r] = fexp2(s0[r] - mm); lsum += s0[r]; }
#pragma unroll
      for (int r = 0; r < 16; ++r) { s1[r] = fexp2(s1[r] - mm); lsum += s1[r]; }
      lsum += __shfl_xor(lsum, 32);
      lstate += lsum;

      // ---- P B-frags in-register (16 cvt_pk + 8 permlane32_swap)
      bf16x8 pb0 = make_pfrag<0>(s0);   // k in [kv0+0,16)
      bf16x8 pb1 = make_pfrag<8>(s0);   // [16,32)
      bf16x8 pb2 = make_pfrag<0>(s1);   // [32,48)
      bf16x8 pb3 = make_pfrag<8>(s1);   // [48,64)

      // ---- O^T += Vt P : A=Vt rows d (ot0: d=q(+0), ot1: d=32+q), B=P cols q
      __builtin_amdgcn_s_setprio(1);
#define PV_STEP(KB, PB)                                                                   \
      {                                                                                   \
        bf16x8 v0 = *(const bf16x8*)&Vl[cur][q * 64 + (((2 * (KB) + hi) ^ (q & 7)) * 8)]; \
        bf16x8 v1 = *(const bf16x8*)&Vl[cur][(32 + q) * 64 + (((2 * (KB) + hi) ^ (q & 7)) * 8)]; \
        ot0 = __builtin_amdgcn_mfma_f32_32x32x16_bf16(v0, PB, ot0, 0, 0, 0);              \
        ot1 = __builtin_amdgcn_mfma_f32_32x32x16_bf16(v1, PB, ot1, 0, 0, 0);              \
      }
      PV_STEP(0, pb0)
      PV_STEP(1, pb1)
      PV_STEP(2, pb2)
      PV_STEP(3, pb3)
#undef PV_STEP
      __builtin_amdgcn_s_setprio(0);
    }
    __syncthreads();
    cur ^= 1;
  }

  // ---- epilogue: O[qw+q][hcol+d] = O^T/l; reg r=4g+j -> d = j + 8g + 4hi (+32 for ot1)
  const float inv = 1.0f / lstate;
  u16* orow = &O[(rowbase + qw + q) * D_MODEL + hcol];
#pragma unroll
  for (int g2 = 0; g2 < 4; ++g2) {
    ushort4 a4 = make_ushort4(f2bf(ot0[4 * g2 + 0] * inv), f2bf(ot0[4 * g2 + 1] * inv),
                              f2bf(ot0[4 * g2 + 2] * inv), f2bf(ot0[4 * g2 + 3] * inv));
    *(ushort4*)&orow[8 * g2 + 4 * hi] = a4;
    ushort4 b4 = make_ushort4(f2bf(ot1[4 * g2 + 0] * inv), f2bf(ot1[4 * g2 + 1] * inv),
                              f2bf(ot1[4 * g2 + 2] * inv), f2bf(ot1[4 * g2 + 3] * inv));
    *(ushort4*)&orow[32 + 8 * g2 + 4 * hi] = b4;
  }
}

// ---------------------------------------------------------------- launch
extern "C" void kernel_launch(void* const* d_in, const int* in_sizes, int n_in,
                              void* d_out, int out_size, void* d_ws, size_t ws_size,
                              hipStream_t stream) {
  const float* x  = (const float*)d_in[0];
  const float* Wq = (const float*)d_in[1];
  const float* Wk = (const float*)d_in[2];
  const float* Wv = (const float*)d_in[3];
  const float* Wo = (const float*)d_in[4];
  float* out = (float*)d_out;

  u16* ws  = (u16*)d_ws;
  u16* xb  = ws;
  u16* wqb = xb + (size_t)NTOK * D_MODEL;
  u16* wkb = wqb + (size_t)D_MODEL * D_MODEL;
  u16* wvb = wkb + (size_t)D_MODEL * D_MODEL;
  u16* wob = wvb + (size_t)D_MODEL * D_MODEL;
  u16* Qb  = wob + (size_t)D_MODEL * D_MODEL;
  u16* Kb  = Qb + (size_t)NTOK * D_MODEL;
  u16* Vb  = Kb + (size_t)NTOK * D_MODEL;   // per-head V^T [B*H*64][SEQ]
  u16* Ob  = xb;  // reuse x's bf16 buffer after projections

  cvt_all<<<2048, 256, 0, stream>>>(x, Wq, Wk, Wv, Wo, xb, wqb, wkb, wvb, wob);

  gemm_qkv<<<dim3(D_MODEL / 128, NTOK / 128, 3), 256, 0, stream>>>(xb, wqb, wkb, wvb, Qb, Kb, Vb);

  attn_fwd<<<dim3(16 * 64), 256, 0, stream>>>(Qb, Kb, Vb, Ob);

  gemm_out<<<dim3(D_MODEL / 128, NTOK / 128), 256, 0, stream>>>(Ob, wob, out);
}

// Round 11
// 185.325 us; speedup vs baseline: 1.3713x; 1.0230x over previous
//
#include <hip/hip_runtime.h>
#include <hip/hip_bf16.h>
#include <stdint.h>

// Problem constants
#define D_MODEL 1024
#define NHEADS  16
#define DKH     64
#define BATCH   4
#define SEQ     2048
#define NTOK    (BATCH * SEQ)   // 8192

typedef unsigned short u16;
using bf16x8 = __attribute__((ext_vector_type(8))) short;   // 8 bf16 = 4 VGPR (MFMA A/B frag)
using f32x4  = __attribute__((ext_vector_type(4))) float;   // 16x16 MFMA C/D frag
using f32x16 = __attribute__((ext_vector_type(16))) float;  // 32x32 MFMA C/D frag
using u32x2  = __attribute__((ext_vector_type(2))) unsigned int;

// async global->LDS, 16B per lane; LDS dest is wave-uniform base (+lane*16 by HW)
#define GLD16(g, l)                                                            \
  __builtin_amdgcn_global_load_lds(                                            \
      (const __attribute__((address_space(1))) void*)(g),                      \
      (__attribute__((address_space(3))) void*)(l), 16, 0, 0)

__device__ inline u16 f2bf(float f) {
  __hip_bfloat16 h = __float2bfloat16(f);
  return __builtin_bit_cast(u16, h);
}

// single v_exp_f32 via intrinsic (compiler inserts TRANS-op hazard nops)
__device__ inline float fexp2(float x) { return __builtin_amdgcn_exp2f(x); }

// packed f32x2 -> bf16x2 (RNE in HW); plain VALU op, T12 recipe (m214v22)
__device__ inline unsigned cvtpk(float lo, float hi) {
  unsigned r;
  asm("v_cvt_pk_bf16_f32 %0, %1, %2" : "=v"(r) : "v"(lo), "v"(hi));
  return r;
}

// Build PV B-frag for one K=16 window from 8 in-register P values (T12):
// lane(q=l&31,hi) holds P[k=crow(r,hi)][q], crow=(r&3)+8*(r>>2)+4*hi.
template <int B>
__device__ inline bf16x8 make_pfrag(const f32x16& sv) {
  unsigned x1 = cvtpk(sv[B + 0], sv[B + 1]);
  unsigned y1 = cvtpk(sv[B + 4], sv[B + 5]);
  unsigned x2 = cvtpk(sv[B + 2], sv[B + 3]);
  unsigned y2 = cvtpk(sv[B + 6], sv[B + 7]);
  u32x2 s1 = __builtin_amdgcn_permlane32_swap(x1, y1, false, false);
  u32x2 s2 = __builtin_amdgcn_permlane32_swap(x2, y2, false, false);
  union { unsigned u[4]; bf16x8 v; } r;
  r.u[0] = s1[0]; r.u[1] = s2[0]; r.u[2] = s1[1]; r.u[3] = s2[1];
  return r.v;
}

// ---------------------------------------------------------------- fused converts
__global__ __launch_bounds__(256) void cvt_all(const float* __restrict__ x,
                                               const float* __restrict__ wq,
                                               const float* __restrict__ wk,
                                               const float* __restrict__ wv,
                                               const float* __restrict__ wo,
                                               u16* xb, u16* wqb, u16* wkb, u16* wvb, u16* wob) {
  const int XC = NTOK * D_MODEL / 4;      // 2097152
  const int WC = D_MODEL * D_MODEL / 4;   // 262144
  const int total = XC + 4 * WC;
  for (int i = blockIdx.x * 256 + threadIdx.x; i < total; i += gridDim.x * 256) {
    const float4* s; ushort4* d; int j;
    if (i < XC)              { s = (const float4*)x;  d = (ushort4*)xb;  j = i; }
    else if (i < XC + WC)    { s = (const float4*)wq; d = (ushort4*)wqb; j = i - XC; }
    else if (i < XC + 2*WC)  { s = (const float4*)wk; d = (ushort4*)wkb; j = i - XC - WC; }
    else if (i < XC + 3*WC)  { s = (const float4*)wv; d = (ushort4*)wvb; j = i - XC - 2*WC; }
    else                     { s = (const float4*)wo; d = (ushort4*)wob; j = i - XC - 3*WC; }
    float4 v = s[j];
    d[j] = make_ushort4(f2bf(v.x), f2bf(v.y), f2bf(v.z), f2bf(v.w));
  }
}

// ---------------------------------------------------------------- fused QKV projection
// A [NTOK,D] bf16; Bq/Bk/Bv [D,D] bf16 (nn.Linear layout, C = A*B^T).
// 2-PHASE DBUF (R11): stage tile k+1 async while computing tile k; one barrier/iter.
// z=0: Q out, scaled 0.125*log2(e). z=1: K. z=2: V transposed per-head.
__global__ __launch_bounds__(256) void gemm_qkv(const u16* __restrict__ A,
                                                const u16* __restrict__ Bq,
                                                const u16* __restrict__ Bk,
                                                const u16* __restrict__ Bv,
                                                u16* __restrict__ Qo,
                                                u16* __restrict__ Ko,
                                                u16* __restrict__ Vo) {
  __shared__ u16 As[2][128 * 64];   // 32 KB
  __shared__ u16 Bs[2][128 * 64];   // 32 KB -> 64 KB total, 2 blocks/CU
  const int z = blockIdx.z;
  const u16* __restrict__ Bp = z == 0 ? Bq : (z == 1 ? Bk : Bv);
  const int t = threadIdx.x, lane = t & 63, wave = t >> 6;
  const int wr = wave >> 1, wc = wave & 1;
  const int frow = lane & 15, fk = (lane >> 4) * 8;
  const int bM = blockIdx.y * 128, bN = blockIdx.x * 128;

  auto stage = [&](int buf, int k0) {
#pragma unroll
    for (int p = 0; p < 4; ++p) {
      int chunk = p * 256 + t;
      int r = chunk >> 3, cc = chunk & 7;
      GLD16(A + (size_t)(bM + r) * D_MODEL + k0 + cc * 8, &As[buf][(size_t)(p * 256 + (t & ~63)) * 8]);
      GLD16(Bp + (size_t)(bN + r) * D_MODEL + k0 + cc * 8, &Bs[buf][(size_t)(p * 256 + (t & ~63)) * 8]);
    }
  };

  f32x4 acc[4][4] = {};
  stage(0, 0);
  __syncthreads();   // buf0 staged (barrier drains vmcnt)

  int cur = 0;
  for (int k0 = 0; k0 < D_MODEL; k0 += 64) {
    if (k0 + 64 < D_MODEL) stage(cur ^ 1, k0 + 64);   // prefetch overlaps compute

    bf16x8 a[2][4], b[2][4];
#pragma unroll
    for (int kk = 0; kk < 2; ++kk) {
#pragma unroll
      for (int m = 0; m < 4; ++m)
        a[kk][m] = *(const bf16x8*)&As[cur][(wr * 64 + m * 16 + frow) * 64 + kk * 32 + fk];
#pragma unroll
      for (int n = 0; n < 4; ++n)
        b[kk][n] = *(const bf16x8*)&Bs[cur][(wc * 64 + n * 16 + frow) * 64 + kk * 32 + fk];
    }
#pragma unroll
    for (int kk = 0; kk < 2; ++kk)
#pragma unroll
      for (int m = 0; m < 4; ++m)
#pragma unroll
        for (int n = 0; n < 4; ++n)
          acc[m][n] = __builtin_amdgcn_mfma_f32_16x16x32_bf16(a[kk][m], b[kk][n], acc[m][n], 0, 0, 0);

    __syncthreads();  // all waves done with cur; prefetch into cur^1 landed
    cur ^= 1;
  }

  const int r0 = bM + wr * 64 + (lane >> 4) * 4;
  const int c0 = bN + wc * 64 + (lane & 15);
  if (z == 2) {
#pragma unroll
    for (int m = 0; m < 4; ++m)
#pragma unroll
      for (int n = 0; n < 4; ++n) {
        int r = r0 + m * 16;   // token (4-aligned, j stays in one batch)
        int cc = c0 + n * 16;  // d_model col
        size_t off = ((size_t)(r >> 11) * D_MODEL + cc) * SEQ + (r & (SEQ - 1));
        *(ushort4*)(Vo + off) = make_ushort4(f2bf(acc[m][n][0]), f2bf(acc[m][n][1]),
                                             f2bf(acc[m][n][2]), f2bf(acc[m][n][3]));
      }
  } else {
    u16* C = z ? Ko : Qo;
    const float sc = z ? 1.0f : 0.18033688f;  // (1/8)*log2(e): softmax in exp2 domain
#pragma unroll
    for (int m = 0; m < 4; ++m)
#pragma unroll
      for (int n = 0; n < 4; ++n)
#pragma unroll
        for (int j = 0; j < 4; ++j)
          C[(size_t)(r0 + m * 16 + j) * D_MODEL + (c0 + n * 16)] = f2bf(acc[m][n][j] * sc);
  }
}

// ---------------------------------------------------------------- output projection C = A*B^T, f32 out
// 2-PHASE DBUF (R11), same structure as gemm_qkv.
__global__ __launch_bounds__(256) void gemm_out(const u16* __restrict__ A,
                                                const u16* __restrict__ B,
                                                float* __restrict__ C) {
  __shared__ u16 As[2][128 * 64];
  __shared__ u16 Bs[2][128 * 64];
  const int t = threadIdx.x, lane = t & 63, wave = t >> 6;
  const int wr = wave >> 1, wc = wave & 1;
  const int frow = lane & 15, fk = (lane >> 4) * 8;
  const int bM = blockIdx.y * 128, bN = blockIdx.x * 128;

  auto stage = [&](int buf, int k0) {
#pragma unroll
    for (int p = 0; p < 4; ++p) {
      int chunk = p * 256 + t;
      int r = chunk >> 3, cc = chunk & 7;
      GLD16(A + (size_t)(bM + r) * D_MODEL + k0 + cc * 8, &As[buf][(size_t)(p * 256 + (t & ~63)) * 8]);
      GLD16(B + (size_t)(bN + r) * D_MODEL + k0 + cc * 8, &Bs[buf][(size_t)(p * 256 + (t & ~63)) * 8]);
    }
  };

  f32x4 acc[4][4] = {};
  stage(0, 0);
  __syncthreads();

  int cur = 0;
  for (int k0 = 0; k0 < D_MODEL; k0 += 64) {
    if (k0 + 64 < D_MODEL) stage(cur ^ 1, k0 + 64);

    bf16x8 a[2][4], b[2][4];
#pragma unroll
    for (int kk = 0; kk < 2; ++kk) {
#pragma unroll
      for (int m = 0; m < 4; ++m)
        a[kk][m] = *(const bf16x8*)&As[cur][(wr * 64 + m * 16 + frow) * 64 + kk * 32 + fk];
#pragma unroll
      for (int n = 0; n < 4; ++n)
        b[kk][n] = *(const bf16x8*)&Bs[cur][(wc * 64 + n * 16 + frow) * 64 + kk * 32 + fk];
    }
#pragma unroll
    for (int kk = 0; kk < 2; ++kk)
#pragma unroll
      for (int m = 0; m < 4; ++m)
#pragma unroll
        for (int n = 0; n < 4; ++n)
          acc[m][n] = __builtin_amdgcn_mfma_f32_16x16x32_bf16(a[kk][m], b[kk][n], acc[m][n], 0, 0, 0);

    __syncthreads();
    cur ^= 1;
  }

  const int r0 = bM + wr * 64 + (lane >> 4) * 4;
  const int c0 = bN + wc * 64 + (lane & 15);
#pragma unroll
  for (int m = 0; m < 4; ++m)
#pragma unroll
    for (int n = 0; n < 4; ++n)
#pragma unroll
      for (int j = 0; j < 4; ++j)
        C[(size_t)(r0 + m * 16 + j) * D_MODEL + (c0 + n * 16)] = acc[m][n][j];
}

// ---------------------------------------------------------------- flash attention (causal)
// 32x32-MFMA structure (R10-proven): 4 waves x 32 q-rows = 128-row q-tile per block.
// Swapped QK^T; softmax lane-local; P in registers via cvt_pk+permlane32_swap (T12);
// O^T=mfma32(Vt,P). K/Vt staged via global_load_lds w/ XOR swizzle, dbuf. defer-max.
__global__ __launch_bounds__(256) void attn_fwd(const u16* __restrict__ Q,
                                                const u16* __restrict__ K,
                                                const u16* __restrict__ Vt,
                                                u16* __restrict__ O) {
  __shared__ u16 Kl[2][64 * 64];   // 16 KB (dbuf)
  __shared__ u16 Vl[2][64 * 64];   // 16 KB (dbuf) -> 32 KB total
  const int t = threadIdx.x, lane = t & 63, wave = t >> 6;
  const int q = lane & 31, hi = lane >> 5;
  const int bh = blockIdx.x & 63;           // bh fastest
  const int qtile = 15 - (blockIdx.x >> 6); // heavy-first
  const int q0 = qtile * 128;
  const size_t rowbase = (size_t)(bh >> 4) * SEQ;
  const int hcol = (bh & 15) * DKH;
  const size_t vbase = (size_t)bh * DKH;
  const int qw = q0 + wave * 32;            // this wave's 32 q-rows
  const int nit = qtile * 2 + 2;

  auto stage = [&](int buf, int kv0) {
#pragma unroll
    for (int pp = 0; pp < 2; ++pp) {
      int chunk = pp * 256 + t;
      int r = chunk >> 3, cc = chunk & 7;
      int cs = cc ^ (r & 7);  // pre-swizzled global source; LDS linear
      GLD16(K + (rowbase + kv0 + r) * D_MODEL + hcol + cs * 8,
            &Kl[buf][(size_t)(pp * 256 + (t & ~63)) * 8]);
      GLD16(Vt + (vbase + r) * SEQ + kv0 + cs * 8,
            &Vl[buf][(size_t)(pp * 256 + (t & ~63)) * 8]);
    }
  };

  stage(0, 0);

  // Q B-frags: lane(q,hi) holds Q[qw+q][w*16 + hi*8 + i], w=0..3 (16 VGPR)
  bf16x8 qf[4];
#pragma unroll
  for (int w = 0; w < 4; ++w)
    qf[w] = *(const bf16x8*)&Q[(rowbase + qw + q) * D_MODEL + hcol + w * 16 + hi * 8];

  f32x16 ot0 = {}, ot1 = {};        // O^T: col q=lane&31, row d=crow(r,hi) (+32 for ot1)
  float mstate = -__builtin_inff();
  float lstate = 0.f;

  __syncthreads();
  int cur = 0;
  for (int it = 0; it < nit; ++it) {
    const int kv0 = it * 64;
    if (it + 1 < nit) stage(cur ^ 1, kv0 + 64);

    if (kv0 <= qw + 31) {  // wave-uniform causal participation
      // ---- S^T tiles: s0 = K[kv0..kv0+31] Q^T, s1 = K[kv0+32..63] Q^T
      f32x16 s0 = {}, s1 = {};
      __builtin_amdgcn_s_setprio(1);
#pragma unroll
      for (int w = 0; w < 4; ++w) {
        const int rk0 = q, rk1 = 32 + q;   // (32+q)&7 == q&7
        bf16x8 k0 = *(const bf16x8*)&Kl[cur][rk0 * 64 + (((2 * w + hi) ^ (rk0 & 7)) * 8)];
        bf16x8 k1 = *(const bf16x8*)&Kl[cur][rk1 * 64 + (((2 * w + hi) ^ (rk0 & 7)) * 8)];
        s0 = __builtin_amdgcn_mfma_f32_32x32x16_bf16(k0, qf[w], s0, 0, 0, 0);
        s1 = __builtin_amdgcn_mfma_f32_32x32x16_bf16(k1, qf[w], s1, 0, 0, 0);
      }
      __builtin_amdgcn_s_setprio(0);

      // ---- mask (diagonal tiles only): k = kv0 + {0,32} + crow(r,hi); q_g = qw+q
      const int qg = qw + q;
      if (kv0 + 63 > qw) {
#pragma unroll
        for (int r = 0; r < 16; ++r) {
          const int crow = (r & 3) + 8 * (r >> 2) + 4 * hi;
          if (kv0 + crow > qg) s0[r] = -__builtin_inff();
          if (kv0 + 32 + crow > qg) s1[r] = -__builtin_inff();
        }
      }

      // ---- lane-local max over 32 vals + 1 cross-half swap
      float pmax = fmaxf(s0[0], s0[1]);
#pragma unroll
      for (int r = 2; r < 16; ++r) pmax = fmaxf(pmax, s0[r]);
#pragma unroll
      for (int r = 0; r < 16; ++r) pmax = fmaxf(pmax, s1[r]);
      pmax = fmaxf(pmax, __shfl_xor(pmax, 32));

      // defer-max (T13), log2 domain: P bounded by 2^11.54 = e^8
      if (__any(pmax > mstate + 11.5416f)) {
        float mnew = fmaxf(mstate, pmax);
        float al = fexp2(mstate - mnew);  // first tile: exp2(-inf)=0
        mstate = mnew;
        lstate *= al;
#pragma unroll
        for (int r = 0; r < 16; ++r) { ot0[r] *= al; ot1[r] *= al; }
      }
      const float mm = mstate;

      // ---- exp (in place) + row-sum
      float lsum = 0.f;
#pragma unroll
      for (int r = 0; r < 16; ++r) { s0[r] = fexp2(s0[r] - mm); lsum += s0[r]; }
#pragma unroll
      for (int r = 0; r < 16; ++r) { s1[r] = fexp2(s1[r] - mm); lsum += s1[r]; }
      lsum += __shfl_xor(lsum, 32);
      lstate += lsum;

      // ---- P B-frags in-register (16 cvt_pk + 8 permlane32_swap)
      bf16x8 pb0 = make_pfrag<0>(s0);   // k in [kv0+0,16)
      bf16x8 pb1 = make_pfrag<8>(s0);   // [16,32)
      bf16x8 pb2 = make_pfrag<0>(s1);   // [32,48)
      bf16x8 pb3 = make_pfrag<8>(s1);   // [48,64)

      // ---- O^T += Vt P : A=Vt rows d (ot0: d=q(+0), ot1: d=32+q), B=P cols q
      __builtin_amdgcn_s_setprio(1);
#define PV_STEP(KB, PB)                                                                   \
      {                                                                                   \
        bf16x8 v0 = *(const bf16x8*)&Vl[cur][q * 64 + (((2 * (KB) + hi) ^ (q & 7)) * 8)]; \
        bf16x8 v1 = *(const bf16x8*)&Vl[cur][(32 + q) * 64 + (((2 * (KB) + hi) ^ (q & 7)) * 8)]; \
        ot0 = __builtin_amdgcn_mfma_f32_32x32x16_bf16(v0, PB, ot0, 0, 0, 0);              \
        ot1 = __builtin_amdgcn_mfma_f32_32x32x16_bf16(v1, PB, ot1, 0, 0, 0);              \
      }
      PV_STEP(0, pb0)
      PV_STEP(1, pb1)
      PV_STEP(2, pb2)
      PV_STEP(3, pb3)
#undef PV_STEP
      __builtin_amdgcn_s_setprio(0);
    }
    __syncthreads();
    cur ^= 1;
  }

  // ---- epilogue: O[qw+q][hcol+d] = O^T/l; reg r=4g+j -> d = j + 8g + 4hi (+32 for ot1)
  const float inv = 1.0f / lstate;
  u16* orow = &O[(rowbase + qw + q) * D_MODEL + hcol];
#pragma unroll
  for (int g2 = 0; g2 < 4; ++g2) {
    ushort4 a4 = make_ushort4(f2bf(ot0[4 * g2 + 0] * inv), f2bf(ot0[4 * g2 + 1] * inv),
                              f2bf(ot0[4 * g2 + 2] * inv), f2bf(ot0[4 * g2 + 3] * inv));
    *(ushort4*)&orow[8 * g2 + 4 * hi] = a4;
    ushort4 b4 = make_ushort4(f2bf(ot1[4 * g2 + 0] * inv), f2bf(ot1[4 * g2 + 1] * inv),
                              f2bf(ot1[4 * g2 + 2] * inv), f2bf(ot1[4 * g2 + 3] * inv));
    *(ushort4*)&orow[32 + 8 * g2 + 4 * hi] = b4;
  }
}

// ---------------------------------------------------------------- launch
extern "C" void kernel_launch(void* const* d_in, const int* in_sizes, int n_in,
                              void* d_out, int out_size, void* d_ws, size_t ws_size,
                              hipStream_t stream) {
  const float* x  = (const float*)d_in[0];
  const float* Wq = (const float*)d_in[1];
  const float* Wk = (const float*)d_in[2];
  const float* Wv = (const float*)d_in[3];
  const float* Wo = (const float*)d_in[4];
  float* out = (float*)d_out;

  u16* ws  = (u16*)d_ws;
  u16* xb  = ws;
  u16* wqb = xb + (size_t)NTOK * D_MODEL;
  u16* wkb = wqb + (size_t)D_MODEL * D_MODEL;
  u16* wvb = wkb + (size_t)D_MODEL * D_MODEL;
  u16* wob = wvb + (size_t)D_MODEL * D_MODEL;
  u16* Qb  = wob + (size_t)D_MODEL * D_MODEL;
  u16* Kb  = Qb + (size_t)NTOK * D_MODEL;
  u16* Vb  = Kb + (size_t)NTOK * D_MODEL;   // per-head V^T [B*H*64][SEQ]
  u16* Ob  = xb;  // reuse x's bf16 buffer after projections

  cvt_all<<<2048, 256, 0, stream>>>(x, Wq, Wk, Wv, Wo, xb, wqb, wkb, wvb, wob);

  gemm_qkv<<<dim3(D_MODEL / 128, NTOK / 128, 3), 256, 0, stream>>>(xb, wqb, wkb, wvb, Qb, Kb, Vb);

  attn_fwd<<<dim3(16 * 64), 256, 0, stream>>>(Qb, Kb, Vb, Ob);

  gemm_out<<<dim3(D_MODEL / 128, NTOK / 128), 256, 0, stream>>>(Ob, wob, out);
}

// Round 12
// 175.336 us; speedup vs baseline: 1.4494x; 1.0570x over previous
//
#include <hip/hip_runtime.h>
#include <hip/hip_bf16.h>
#include <stdint.h>

// Problem constants
#define D_MODEL 1024
#define NHEADS  16
#define DKH     64
#define BATCH   4
#define SEQ     2048
#define NTOK    (BATCH * SEQ)   // 8192

typedef unsigned short u16;
using bf16x8 = __attribute__((ext_vector_type(8))) short;   // 8 bf16 = 4 VGPR (MFMA A/B frag)
using f32x4  = __attribute__((ext_vector_type(4))) float;   // 16x16 MFMA C/D frag
using f32x16 = __attribute__((ext_vector_type(16))) float;  // 32x32 MFMA C/D frag
using u32x2  = __attribute__((ext_vector_type(2))) unsigned int;

// async global->LDS, 16B per lane; LDS dest is wave-uniform base (+lane*16 by HW)
#define GLD16(g, l)                                                            \
  __builtin_amdgcn_global_load_lds(                                            \
      (const __attribute__((address_space(1))) void*)(g),                      \
      (__attribute__((address_space(3))) void*)(l), 16, 0, 0)

__device__ inline u16 f2bf(float f) {
  __hip_bfloat16 h = __float2bfloat16(f);
  return __builtin_bit_cast(u16, h);
}

// single v_exp_f32 via intrinsic (compiler inserts TRANS-op hazard nops)
__device__ inline float fexp2(float x) { return __builtin_amdgcn_exp2f(x); }

// packed f32x2 -> bf16x2 (RNE in HW); plain VALU op, T12 recipe (m214v22)
__device__ inline unsigned cvtpk(float lo, float hi) {
  unsigned r;
  asm("v_cvt_pk_bf16_f32 %0, %1, %2" : "=v"(r) : "v"(lo), "v"(hi));
  return r;
}

// Build PV B-frag for one K=16 window from 8 in-register P values (T12)
template <int B>
__device__ inline bf16x8 make_pfrag(const f32x16& sv) {
  unsigned x1 = cvtpk(sv[B + 0], sv[B + 1]);
  unsigned y1 = cvtpk(sv[B + 4], sv[B + 5]);
  unsigned x2 = cvtpk(sv[B + 2], sv[B + 3]);
  unsigned y2 = cvtpk(sv[B + 6], sv[B + 7]);
  u32x2 s1 = __builtin_amdgcn_permlane32_swap(x1, y1, false, false);
  u32x2 s2 = __builtin_amdgcn_permlane32_swap(x2, y2, false, false);
  union { unsigned u[4]; bf16x8 v; } r;
  r.u[0] = s1[0]; r.u[1] = s2[0]; r.u[2] = s1[1]; r.u[3] = s2[1];
  return r.v;
}

// ---------------------------------------------------------------- fused converts
__global__ __launch_bounds__(256) void cvt_all(const float* __restrict__ x,
                                               const float* __restrict__ wq,
                                               const float* __restrict__ wk,
                                               const float* __restrict__ wv,
                                               const float* __restrict__ wo,
                                               u16* xb, u16* wqb, u16* wkb, u16* wvb, u16* wob) {
  const int XC = NTOK * D_MODEL / 4;      // 2097152
  const int WC = D_MODEL * D_MODEL / 4;   // 262144
  const int total = XC + 4 * WC;
  for (int i = blockIdx.x * 256 + threadIdx.x; i < total; i += gridDim.x * 256) {
    const float4* s; ushort4* d; int j;
    if (i < XC)              { s = (const float4*)x;  d = (ushort4*)xb;  j = i; }
    else if (i < XC + WC)    { s = (const float4*)wq; d = (ushort4*)wqb; j = i - XC; }
    else if (i < XC + 2*WC)  { s = (const float4*)wk; d = (ushort4*)wkb; j = i - XC - WC; }
    else if (i < XC + 3*WC)  { s = (const float4*)wv; d = (ushort4*)wvb; j = i - XC - 2*WC; }
    else                     { s = (const float4*)wo; d = (ushort4*)wob; j = i - XC - 3*WC; }
    float4 v = s[j];
    d[j] = make_ushort4(f2bf(v.x), f2bf(v.y), f2bf(v.z), f2bf(v.w));
  }
}

// ---------------------------------------------------------------- fused QKV projection
// A [NTOK,D] bf16; Bq/Bk/Bv [D,D] bf16 (nn.Linear layout, C = A*B^T).
// 2-phase dbuf + T1 XCD-chunk swizzle (R12): linearize L = z*512 + bM*8 + bN (bN inner),
// logical L = (h%8)*192 + h/8  ->  each XCD owns one contiguous chunk: single z
// (B weights 2MB L2-resident) x 24 A-panels with all 8 uses temporally adjacent.
// z=0: Q out, scaled 0.125*log2(e). z=1: K. z=2: V transposed per-head.
__global__ __launch_bounds__(256) void gemm_qkv(const u16* __restrict__ A,
                                                const u16* __restrict__ Bq,
                                                const u16* __restrict__ Bk,
                                                const u16* __restrict__ Bv,
                                                u16* __restrict__ Qo,
                                                u16* __restrict__ Ko,
                                                u16* __restrict__ Vo) {
  __shared__ u16 As[2][128 * 64];   // 32 KB
  __shared__ u16 Bs[2][128 * 64];   // 32 KB -> 64 KB total, 2 blocks/CU
  const int h = blockIdx.x;
  const int L = (h & 7) * 192 + (h >> 3);   // bijective XCD-chunk swizzle (nwg=1536)
  const int z = L / 512;
  const int rr = L % 512;
  const int bM = (rr >> 3) * 128;
  const int bN = (rr & 7) * 128;
  const u16* __restrict__ Bp = z == 0 ? Bq : (z == 1 ? Bk : Bv);
  const int t = threadIdx.x, lane = t & 63, wave = t >> 6;
  const int wr = wave >> 1, wc = wave & 1;
  const int frow = lane & 15, fk = (lane >> 4) * 8;

  auto stage = [&](int buf, int k0) {
#pragma unroll
    for (int p = 0; p < 4; ++p) {
      int chunk = p * 256 + t;
      int r = chunk >> 3, cc = chunk & 7;
      GLD16(A + (size_t)(bM + r) * D_MODEL + k0 + cc * 8, &As[buf][(size_t)(p * 256 + (t & ~63)) * 8]);
      GLD16(Bp + (size_t)(bN + r) * D_MODEL + k0 + cc * 8, &Bs[buf][(size_t)(p * 256 + (t & ~63)) * 8]);
    }
  };

  f32x4 acc[4][4] = {};
  stage(0, 0);
  __syncthreads();   // buf0 staged (barrier drains vmcnt)

  int cur = 0;
  for (int k0 = 0; k0 < D_MODEL; k0 += 64) {
    if (k0 + 64 < D_MODEL) stage(cur ^ 1, k0 + 64);   // prefetch overlaps compute

    bf16x8 a[2][4], b[2][4];
#pragma unroll
    for (int kk = 0; kk < 2; ++kk) {
#pragma unroll
      for (int m = 0; m < 4; ++m)
        a[kk][m] = *(const bf16x8*)&As[cur][(wr * 64 + m * 16 + frow) * 64 + kk * 32 + fk];
#pragma unroll
      for (int n = 0; n < 4; ++n)
        b[kk][n] = *(const bf16x8*)&Bs[cur][(wc * 64 + n * 16 + frow) * 64 + kk * 32 + fk];
    }
#pragma unroll
    for (int kk = 0; kk < 2; ++kk)
#pragma unroll
      for (int m = 0; m < 4; ++m)
#pragma unroll
        for (int n = 0; n < 4; ++n)
          acc[m][n] = __builtin_amdgcn_mfma_f32_16x16x32_bf16(a[kk][m], b[kk][n], acc[m][n], 0, 0, 0);

    __syncthreads();  // all waves done with cur; prefetch into cur^1 landed
    cur ^= 1;
  }

  const int r0 = bM + wr * 64 + (lane >> 4) * 4;
  const int c0 = bN + wc * 64 + (lane & 15);
  if (z == 2) {
#pragma unroll
    for (int m = 0; m < 4; ++m)
#pragma unroll
      for (int n = 0; n < 4; ++n) {
        int r = r0 + m * 16;   // token (4-aligned, j stays in one batch)
        int cc = c0 + n * 16;  // d_model col
        size_t off = ((size_t)(r >> 11) * D_MODEL + cc) * SEQ + (r & (SEQ - 1));
        *(ushort4*)(Vo + off) = make_ushort4(f2bf(acc[m][n][0]), f2bf(acc[m][n][1]),
                                             f2bf(acc[m][n][2]), f2bf(acc[m][n][3]));
      }
  } else {
    u16* C = z ? Ko : Qo;
    const float sc = z ? 1.0f : 0.18033688f;  // (1/8)*log2(e): softmax in exp2 domain
#pragma unroll
    for (int m = 0; m < 4; ++m)
#pragma unroll
      for (int n = 0; n < 4; ++n)
#pragma unroll
        for (int j = 0; j < 4; ++j)
          C[(size_t)(r0 + m * 16 + j) * D_MODEL + (c0 + n * 16)] = f2bf(acc[m][n][j] * sc);
  }
}

// ---------------------------------------------------------------- output projection C = A*B^T, f32 out
// 2-phase dbuf + T1 XCD-chunk swizzle (nwg=512, cpx=64).
__global__ __launch_bounds__(256) void gemm_out(const u16* __restrict__ A,
                                                const u16* __restrict__ B,
                                                float* __restrict__ C) {
  __shared__ u16 As[2][128 * 64];
  __shared__ u16 Bs[2][128 * 64];
  const int h = blockIdx.x;
  const int L = (h & 7) * 64 + (h >> 3);    // bijective XCD-chunk swizzle (nwg=512)
  const int bM = (L >> 3) * 128;
  const int bN = (L & 7) * 128;
  const int t = threadIdx.x, lane = t & 63, wave = t >> 6;
  const int wr = wave >> 1, wc = wave & 1;
  const int frow = lane & 15, fk = (lane >> 4) * 8;

  auto stage = [&](int buf, int k0) {
#pragma unroll
    for (int p = 0; p < 4; ++p) {
      int chunk = p * 256 + t;
      int r = chunk >> 3, cc = chunk & 7;
      GLD16(A + (size_t)(bM + r) * D_MODEL + k0 + cc * 8, &As[buf][(size_t)(p * 256 + (t & ~63)) * 8]);
      GLD16(B + (size_t)(bN + r) * D_MODEL + k0 + cc * 8, &Bs[buf][(size_t)(p * 256 + (t & ~63)) * 8]);
    }
  };

  f32x4 acc[4][4] = {};
  stage(0, 0);
  __syncthreads();

  int cur = 0;
  for (int k0 = 0; k0 < D_MODEL; k0 += 64) {
    if (k0 + 64 < D_MODEL) stage(cur ^ 1, k0 + 64);

    bf16x8 a[2][4], b[2][4];
#pragma unroll
    for (int kk = 0; kk < 2; ++kk) {
#pragma unroll
      for (int m = 0; m < 4; ++m)
        a[kk][m] = *(const bf16x8*)&As[cur][(wr * 64 + m * 16 + frow) * 64 + kk * 32 + fk];
#pragma unroll
      for (int n = 0; n < 4; ++n)
        b[kk][n] = *(const bf16x8*)&Bs[cur][(wc * 64 + n * 16 + frow) * 64 + kk * 32 + fk];
    }
#pragma unroll
    for (int kk = 0; kk < 2; ++kk)
#pragma unroll
      for (int m = 0; m < 4; ++m)
#pragma unroll
        for (int n = 0; n < 4; ++n)
          acc[m][n] = __builtin_amdgcn_mfma_f32_16x16x32_bf16(a[kk][m], b[kk][n], acc[m][n], 0, 0, 0);

    __syncthreads();
    cur ^= 1;
  }

  const int r0 = bM + wr * 64 + (lane >> 4) * 4;
  const int c0 = bN + wc * 64 + (lane & 15);
#pragma unroll
  for (int m = 0; m < 4; ++m)
#pragma unroll
    for (int n = 0; n < 4; ++n)
#pragma unroll
      for (int j = 0; j < 4; ++j)
        C[(size_t)(r0 + m * 16 + j) * D_MODEL + (c0 + n * 16)] = acc[m][n][j];
}

// ---------------------------------------------------------------- flash attention (causal)
// 32x32-MFMA structure (R10-proven): 4 waves x 32 q-rows = 128-row q-tile per block.
// Swapped QK^T; softmax lane-local; P in registers via cvt_pk+permlane32_swap (T12);
// O^T=mfma32(Vt,P). K/Vt staged via global_load_lds w/ XOR swizzle, dbuf. defer-max.
// Grid: bh fastest -> same-bh blocks land on same XCD (64%8==0), KV L2-resident.
__global__ __launch_bounds__(256) void attn_fwd(const u16* __restrict__ Q,
                                                const u16* __restrict__ K,
                                                const u16* __restrict__ Vt,
                                                u16* __restrict__ O) {
  __shared__ u16 Kl[2][64 * 64];   // 16 KB (dbuf)
  __shared__ u16 Vl[2][64 * 64];   // 16 KB (dbuf) -> 32 KB total
  const int t = threadIdx.x, lane = t & 63, wave = t >> 6;
  const int q = lane & 31, hi = lane >> 5;
  const int bh = blockIdx.x & 63;           // bh fastest
  const int qtile = 15 - (blockIdx.x >> 6); // heavy-first
  const int q0 = qtile * 128;
  const size_t rowbase = (size_t)(bh >> 4) * SEQ;
  const int hcol = (bh & 15) * DKH;
  const size_t vbase = (size_t)bh * DKH;
  const int qw = q0 + wave * 32;            // this wave's 32 q-rows
  const int nit = qtile * 2 + 2;

  auto stage = [&](int buf, int kv0) {
#pragma unroll
    for (int pp = 0; pp < 2; ++pp) {
      int chunk = pp * 256 + t;
      int r = chunk >> 3, cc = chunk & 7;
      int cs = cc ^ (r & 7);  // pre-swizzled global source; LDS linear
      GLD16(K + (rowbase + kv0 + r) * D_MODEL + hcol + cs * 8,
            &Kl[buf][(size_t)(pp * 256 + (t & ~63)) * 8]);
      GLD16(Vt + (vbase + r) * SEQ + kv0 + cs * 8,
            &Vl[buf][(size_t)(pp * 256 + (t & ~63)) * 8]);
    }
  };

  stage(0, 0);

  // Q B-frags: lane(q,hi) holds Q[qw+q][w*16 + hi*8 + i], w=0..3 (16 VGPR)
  bf16x8 qf[4];
#pragma unroll
  for (int w = 0; w < 4; ++w)
    qf[w] = *(const bf16x8*)&Q[(rowbase + qw + q) * D_MODEL + hcol + w * 16 + hi * 8];

  f32x16 ot0 = {}, ot1 = {};        // O^T: col q=lane&31, row d=crow(r,hi) (+32 for ot1)
  float mstate = -__builtin_inff();
  float lstate = 0.f;

  __syncthreads();
  int cur = 0;
  for (int it = 0; it < nit; ++it) {
    const int kv0 = it * 64;
    if (it + 1 < nit) stage(cur ^ 1, kv0 + 64);

    if (kv0 <= qw + 31) {  // wave-uniform causal participation
      // ---- S^T tiles: s0 = K[kv0..kv0+31] Q^T, s1 = K[kv0+32..63] Q^T
      f32x16 s0 = {}, s1 = {};
      __builtin_amdgcn_s_setprio(1);
#pragma unroll
      for (int w = 0; w < 4; ++w) {
        const int rk0 = q, rk1 = 32 + q;   // (32+q)&7 == q&7
        bf16x8 k0 = *(const bf16x8*)&Kl[cur][rk0 * 64 + (((2 * w + hi) ^ (rk0 & 7)) * 8)];
        bf16x8 k1 = *(const bf16x8*)&Kl[cur][rk1 * 64 + (((2 * w + hi) ^ (rk0 & 7)) * 8)];
        s0 = __builtin_amdgcn_mfma_f32_32x32x16_bf16(k0, qf[w], s0, 0, 0, 0);
        s1 = __builtin_amdgcn_mfma_f32_32x32x16_bf16(k1, qf[w], s1, 0, 0, 0);
      }
      __builtin_amdgcn_s_setprio(0);

      // ---- mask (diagonal tiles only): k = kv0 + {0,32} + crow(r,hi); q_g = qw+q
      const int qg = qw + q;
      if (kv0 + 63 > qw) {
#pragma unroll
        for (int r = 0; r < 16; ++r) {
          const int crow = (r & 3) + 8 * (r >> 2) + 4 * hi;
          if (kv0 + crow > qg) s0[r] = -__builtin_inff();
          if (kv0 + 32 + crow > qg) s1[r] = -__builtin_inff();
        }
      }

      // ---- lane-local max over 32 vals + 1 cross-half swap
      float pmax = fmaxf(s0[0], s0[1]);
#pragma unroll
      for (int r = 2; r < 16; ++r) pmax = fmaxf(pmax, s0[r]);
#pragma unroll
      for (int r = 0; r < 16; ++r) pmax = fmaxf(pmax, s1[r]);
      pmax = fmaxf(pmax, __shfl_xor(pmax, 32));

      // defer-max (T13), log2 domain: P bounded by 2^11.54 = e^8
      if (__any(pmax > mstate + 11.5416f)) {
        float mnew = fmaxf(mstate, pmax);
        float al = fexp2(mstate - mnew);  // first tile: exp2(-inf)=0
        mstate = mnew;
        lstate *= al;
#pragma unroll
        for (int r = 0; r < 16; ++r) { ot0[r] *= al; ot1[r] *= al; }
      }
      const float mm = mstate;

      // ---- exp (in place) + row-sum
      float lsum = 0.f;
#pragma unroll
      for (int r = 0; r < 16; ++r) { s0[r] = fexp2(s0[r] - mm); lsum += s0[r]; }
#pragma unroll
      for (int r = 0; r < 16; ++r) { s1[r] = fexp2(s1[r] - mm); lsum += s1[r]; }
      lsum += __shfl_xor(lsum, 32);
      lstate += lsum;

      // ---- P B-frags in-register (16 cvt_pk + 8 permlane32_swap)
      bf16x8 pb0 = make_pfrag<0>(s0);   // k in [kv0+0,16)
      bf16x8 pb1 = make_pfrag<8>(s0);   // [16,32)
      bf16x8 pb2 = make_pfrag<0>(s1);   // [32,48)
      bf16x8 pb3 = make_pfrag<8>(s1);   // [48,64)

      // ---- O^T += Vt P : A=Vt rows d (ot0: d=q(+0), ot1: d=32+q), B=P cols q
      __builtin_amdgcn_s_setprio(1);
#define PV_STEP(KB, PB)                                                                   \
      {                                                                                   \
        bf16x8 v0 = *(const bf16x8*)&Vl[cur][q * 64 + (((2 * (KB) + hi) ^ (q & 7)) * 8)]; \
        bf16x8 v1 = *(const bf16x8*)&Vl[cur][(32 + q) * 64 + (((2 * (KB) + hi) ^ (q & 7)) * 8)]; \
        ot0 = __builtin_amdgcn_mfma_f32_32x32x16_bf16(v0, PB, ot0, 0, 0, 0);              \
        ot1 = __builtin_amdgcn_mfma_f32_32x32x16_bf16(v1, PB, ot1, 0, 0, 0);              \
      }
      PV_STEP(0, pb0)
      PV_STEP(1, pb1)
      PV_STEP(2, pb2)
      PV_STEP(3, pb3)
#undef PV_STEP
      __builtin_amdgcn_s_setprio(0);
    }
    __syncthreads();
    cur ^= 1;
  }

  // ---- epilogue: O[qw+q][hcol+d] = O^T/l; reg r=4g+j -> d = j + 8g + 4hi (+32 for ot1)
  const float inv = 1.0f / lstate;
  u16* orow = &O[(rowbase + qw + q) * D_MODEL + hcol];
#pragma unroll
  for (int g2 = 0; g2 < 4; ++g2) {
    ushort4 a4 = make_ushort4(f2bf(ot0[4 * g2 + 0] * inv), f2bf(ot0[4 * g2 + 1] * inv),
                              f2bf(ot0[4 * g2 + 2] * inv), f2bf(ot0[4 * g2 + 3] * inv));
    *(ushort4*)&orow[8 * g2 + 4 * hi] = a4;
    ushort4 b4 = make_ushort4(f2bf(ot1[4 * g2 + 0] * inv), f2bf(ot1[4 * g2 + 1] * inv),
                              f2bf(ot1[4 * g2 + 2] * inv), f2bf(ot1[4 * g2 + 3] * inv));
    *(ushort4*)&orow[32 + 8 * g2 + 4 * hi] = b4;
  }
}

// ---------------------------------------------------------------- launch
extern "C" void kernel_launch(void* const* d_in, const int* in_sizes, int n_in,
                              void* d_out, int out_size, void* d_ws, size_t ws_size,
                              hipStream_t stream) {
  const float* x  = (const float*)d_in[0];
  const float* Wq = (const float*)d_in[1];
  const float* Wk = (const float*)d_in[2];
  const float* Wv = (const float*)d_in[3];
  const float* Wo = (const float*)d_in[4];
  float* out = (float*)d_out;

  u16* ws  = (u16*)d_ws;
  u16* xb  = ws;
  u16* wqb = xb + (size_t)NTOK * D_MODEL;
  u16* wkb = wqb + (size_t)D_MODEL * D_MODEL;
  u16* wvb = wkb + (size_t)D_MODEL * D_MODEL;
  u16* wob = wvb + (size_t)D_MODEL * D_MODEL;
  u16* Qb  = wob + (size_t)D_MODEL * D_MODEL;
  u16* Kb  = Qb + (size_t)NTOK * D_MODEL;
  u16* Vb  = Kb + (size_t)NTOK * D_MODEL;   // per-head V^T [B*H*64][SEQ]
  u16* Ob  = xb;  // reuse x's bf16 buffer after projections

  cvt_all<<<2048, 256, 0, stream>>>(x, Wq, Wk, Wv, Wo, xb, wqb, wkb, wvb, wob);

  gemm_qkv<<<1536, 256, 0, stream>>>(xb, wqb, wkb, wvb, Qb, Kb, Vb);

  attn_fwd<<<dim3(16 * 64), 256, 0, stream>>>(Qb, Kb, Vb, Ob);

  gemm_out<<<512, 256, 0, stream>>>(Ob, wob, out);
}

// Round 13
// 164.046 us; speedup vs baseline: 1.5492x; 1.0688x over previous
//
#include <hip/hip_runtime.h>
#include <hip/hip_bf16.h>
#include <stdint.h>

// Problem constants
#define D_MODEL 1024
#define NHEADS  16
#define DKH     64
#define BATCH   4
#define SEQ     2048
#define NTOK    (BATCH * SEQ)   // 8192

typedef unsigned short u16;
using bf16x8 = __attribute__((ext_vector_type(8))) short;   // 8 bf16 = 4 VGPR (MFMA A/B frag)
using f32x4  = __attribute__((ext_vector_type(4))) float;   // 16x16 MFMA C/D frag
using f32x16 = __attribute__((ext_vector_type(16))) float;  // 32x32 MFMA C/D frag
using u32x2  = __attribute__((ext_vector_type(2))) unsigned int;

// async global->LDS, 16B per lane; LDS dest is wave-uniform base (+lane*16 by HW)
#define GLD16(g, l)                                                            \
  __builtin_amdgcn_global_load_lds(                                            \
      (const __attribute__((address_space(1))) void*)(g),                      \
      (__attribute__((address_space(3))) void*)(l), 16, 0, 0)

__device__ inline u16 f2bf(float f) {
  __hip_bfloat16 h = __float2bfloat16(f);
  return __builtin_bit_cast(u16, h);
}

// single v_exp_f32 via intrinsic (compiler inserts TRANS-op hazard nops)
__device__ inline float fexp2(float x) { return __builtin_amdgcn_exp2f(x); }

// packed f32x2 -> bf16x2 (RNE in HW); plain VALU op, T12 recipe (m214v22)
__device__ inline unsigned cvtpk(float lo, float hi) {
  unsigned r;
  asm("v_cvt_pk_bf16_f32 %0, %1, %2" : "=v"(r) : "v"(lo), "v"(hi));
  return r;
}

// Build PV B-frag for one K=16 window from 8 in-register P values (T12)
template <int B>
__device__ inline bf16x8 make_pfrag(const f32x16& sv) {
  unsigned x1 = cvtpk(sv[B + 0], sv[B + 1]);
  unsigned y1 = cvtpk(sv[B + 4], sv[B + 5]);
  unsigned x2 = cvtpk(sv[B + 2], sv[B + 3]);
  unsigned y2 = cvtpk(sv[B + 6], sv[B + 7]);
  u32x2 s1 = __builtin_amdgcn_permlane32_swap(x1, y1, false, false);
  u32x2 s2 = __builtin_amdgcn_permlane32_swap(x2, y2, false, false);
  union { unsigned u[4]; bf16x8 v; } r;
  r.u[0] = s1[0]; r.u[1] = s2[0]; r.u[2] = s1[1]; r.u[3] = s2[1];
  return r.v;
}

// ---------------------------------------------------------------- fused converts
__global__ __launch_bounds__(256) void cvt_all(const float* __restrict__ x,
                                               const float* __restrict__ wq,
                                               const float* __restrict__ wk,
                                               const float* __restrict__ wv,
                                               const float* __restrict__ wo,
                                               u16* xb, u16* wqb, u16* wkb, u16* wvb, u16* wob) {
  const int XC = NTOK * D_MODEL / 4;      // 2097152
  const int WC = D_MODEL * D_MODEL / 4;   // 262144
  const int total = XC + 4 * WC;
  for (int i = blockIdx.x * 256 + threadIdx.x; i < total; i += gridDim.x * 256) {
    const float4* s; ushort4* d; int j;
    if (i < XC)              { s = (const float4*)x;  d = (ushort4*)xb;  j = i; }
    else if (i < XC + WC)    { s = (const float4*)wq; d = (ushort4*)wqb; j = i - XC; }
    else if (i < XC + 2*WC)  { s = (const float4*)wk; d = (ushort4*)wkb; j = i - XC - WC; }
    else if (i < XC + 3*WC)  { s = (const float4*)wv; d = (ushort4*)wvb; j = i - XC - 2*WC; }
    else                     { s = (const float4*)wo; d = (ushort4*)wob; j = i - XC - 3*WC; }
    float4 v = s[j];
    d[j] = make_ushort4(f2bf(v.x), f2bf(v.y), f2bf(v.z), f2bf(v.w));
  }
}

// ---------------------------------------------------------------- fused QKV projection
// A [NTOK,D] bf16; Bq/Bk/Bv [D,D] bf16 (nn.Linear layout, C = A*B^T).
// 2-phase dbuf + T1 XCD-chunk swizzle + T2 LDS XOR-swizzle (R13):
// stage source chunk cs = cc^(r&7) (LDS dest linear, rule #21), frag reads XOR
// chunk with frow&7 -> ds_read_b128 2-way max (free) instead of 16-way.
// z=0: Q out, scaled 0.125*log2(e). z=1: K. z=2: V transposed per-head.
__global__ __launch_bounds__(256) void gemm_qkv(const u16* __restrict__ A,
                                                const u16* __restrict__ Bq,
                                                const u16* __restrict__ Bk,
                                                const u16* __restrict__ Bv,
                                                u16* __restrict__ Qo,
                                                u16* __restrict__ Ko,
                                                u16* __restrict__ Vo) {
  __shared__ u16 As[2][128 * 64];   // 32 KB
  __shared__ u16 Bs[2][128 * 64];   // 32 KB -> 64 KB total, 2 blocks/CU
  const int h = blockIdx.x;
  const int L = (h & 7) * 192 + (h >> 3);   // bijective XCD-chunk swizzle (nwg=1536)
  const int z = L / 512;
  const int rr = L % 512;
  const int bM = (rr >> 3) * 128;
  const int bN = (rr & 7) * 128;
  const u16* __restrict__ Bp = z == 0 ? Bq : (z == 1 ? Bk : Bv);
  const int t = threadIdx.x, lane = t & 63, wave = t >> 6;
  const int wr = wave >> 1, wc = wave & 1;
  const int frow = lane & 15, g = lane >> 4;

  auto stage = [&](int buf, int k0) {
#pragma unroll
    for (int p = 0; p < 4; ++p) {
      int chunk = p * 256 + t;
      int r = chunk >> 3, cc = chunk & 7;
      int cs = cc ^ (r & 7);   // pre-swizzled source; LDS linear (T2 via rule #21)
      GLD16(A + (size_t)(bM + r) * D_MODEL + k0 + cs * 8, &As[buf][(size_t)(p * 256 + (t & ~63)) * 8]);
      GLD16(Bp + (size_t)(bN + r) * D_MODEL + k0 + cs * 8, &Bs[buf][(size_t)(p * 256 + (t & ~63)) * 8]);
    }
  };

  f32x4 acc[4][4] = {};
  stage(0, 0);
  __syncthreads();   // buf0 staged (barrier drains vmcnt)

  int cur = 0;
  for (int k0 = 0; k0 < D_MODEL; k0 += 64) {
    if (k0 + 64 < D_MODEL) stage(cur ^ 1, k0 + 64);   // prefetch overlaps compute

    bf16x8 a[2][4], b[2][4];
#pragma unroll
    for (int kk = 0; kk < 2; ++kk) {
#pragma unroll
      for (int m = 0; m < 4; ++m)
        a[kk][m] = *(const bf16x8*)&As[cur][(wr * 64 + m * 16 + frow) * 64 +
                                           (((kk * 4 + g) ^ (frow & 7)) * 8)];
#pragma unroll
      for (int n = 0; n < 4; ++n)
        b[kk][n] = *(const bf16x8*)&Bs[cur][(wc * 64 + n * 16 + frow) * 64 +
                                           (((kk * 4 + g) ^ (frow & 7)) * 8)];
    }
#pragma unroll
    for (int kk = 0; kk < 2; ++kk)
#pragma unroll
      for (int m = 0; m < 4; ++m)
#pragma unroll
        for (int n = 0; n < 4; ++n)
          acc[m][n] = __builtin_amdgcn_mfma_f32_16x16x32_bf16(a[kk][m], b[kk][n], acc[m][n], 0, 0, 0);

    __syncthreads();  // all waves done with cur; prefetch into cur^1 landed
    cur ^= 1;
  }

  const int r0 = bM + wr * 64 + (lane >> 4) * 4;
  const int c0 = bN + wc * 64 + (lane & 15);
  if (z == 2) {
#pragma unroll
    for (int m = 0; m < 4; ++m)
#pragma unroll
      for (int n = 0; n < 4; ++n) {
        int r = r0 + m * 16;   // token (4-aligned, j stays in one batch)
        int cc = c0 + n * 16;  // d_model col
        size_t off = ((size_t)(r >> 11) * D_MODEL + cc) * SEQ + (r & (SEQ - 1));
        *(ushort4*)(Vo + off) = make_ushort4(f2bf(acc[m][n][0]), f2bf(acc[m][n][1]),
                                             f2bf(acc[m][n][2]), f2bf(acc[m][n][3]));
      }
  } else {
    u16* C = z ? Ko : Qo;
    const float sc = z ? 1.0f : 0.18033688f;  // (1/8)*log2(e): softmax in exp2 domain
#pragma unroll
    for (int m = 0; m < 4; ++m)
#pragma unroll
      for (int n = 0; n < 4; ++n)
#pragma unroll
        for (int j = 0; j < 4; ++j)
          C[(size_t)(r0 + m * 16 + j) * D_MODEL + (c0 + n * 16)] = f2bf(acc[m][n][j] * sc);
  }
}

// ---------------------------------------------------------------- output projection C = A*B^T, f32 out
// 2-phase dbuf + T1 XCD swizzle + T2 LDS XOR-swizzle (same as gemm_qkv).
__global__ __launch_bounds__(256) void gemm_out(const u16* __restrict__ A,
                                                const u16* __restrict__ B,
                                                float* __restrict__ C) {
  __shared__ u16 As[2][128 * 64];
  __shared__ u16 Bs[2][128 * 64];
  const int h = blockIdx.x;
  const int L = (h & 7) * 64 + (h >> 3);    // bijective XCD-chunk swizzle (nwg=512)
  const int bM = (L >> 3) * 128;
  const int bN = (L & 7) * 128;
  const int t = threadIdx.x, lane = t & 63, wave = t >> 6;
  const int wr = wave >> 1, wc = wave & 1;
  const int frow = lane & 15, g = lane >> 4;

  auto stage = [&](int buf, int k0) {
#pragma unroll
    for (int p = 0; p < 4; ++p) {
      int chunk = p * 256 + t;
      int r = chunk >> 3, cc = chunk & 7;
      int cs = cc ^ (r & 7);   // pre-swizzled source; LDS linear
      GLD16(A + (size_t)(bM + r) * D_MODEL + k0 + cs * 8, &As[buf][(size_t)(p * 256 + (t & ~63)) * 8]);
      GLD16(B + (size_t)(bN + r) * D_MODEL + k0 + cs * 8, &Bs[buf][(size_t)(p * 256 + (t & ~63)) * 8]);
    }
  };

  f32x4 acc[4][4] = {};
  stage(0, 0);
  __syncthreads();

  int cur = 0;
  for (int k0 = 0; k0 < D_MODEL; k0 += 64) {
    if (k0 + 64 < D_MODEL) stage(cur ^ 1, k0 + 64);

    bf16x8 a[2][4], b[2][4];
#pragma unroll
    for (int kk = 0; kk < 2; ++kk) {
#pragma unroll
      for (int m = 0; m < 4; ++m)
        a[kk][m] = *(const bf16x8*)&As[cur][(wr * 64 + m * 16 + frow) * 64 +
                                           (((kk * 4 + g) ^ (frow & 7)) * 8)];
#pragma unroll
      for (int n = 0; n < 4; ++n)
        b[kk][n] = *(const bf16x8*)&Bs[cur][(wc * 64 + n * 16 + frow) * 64 +
                                           (((kk * 4 + g) ^ (frow & 7)) * 8)];
    }
#pragma unroll
    for (int kk = 0; kk < 2; ++kk)
#pragma unroll
      for (int m = 0; m < 4; ++m)
#pragma unroll
        for (int n = 0; n < 4; ++n)
          acc[m][n] = __builtin_amdgcn_mfma_f32_16x16x32_bf16(a[kk][m], b[kk][n], acc[m][n], 0, 0, 0);

    __syncthreads();
    cur ^= 1;
  }

  const int r0 = bM + wr * 64 + (lane >> 4) * 4;
  const int c0 = bN + wc * 64 + (lane & 15);
#pragma unroll
  for (int m = 0; m < 4; ++m)
#pragma unroll
    for (int n = 0; n < 4; ++n)
#pragma unroll
      for (int j = 0; j < 4; ++j)
        C[(size_t)(r0 + m * 16 + j) * D_MODEL + (c0 + n * 16)] = acc[m][n][j];
}

// ---------------------------------------------------------------- flash attention (causal)
// 32x32-MFMA structure (R10-proven): 4 waves x 32 q-rows = 128-row q-tile per block.
// Swapped QK^T; softmax lane-local; P in registers via cvt_pk+permlane32_swap (T12);
// O^T=mfma32(Vt,P). K/Vt staged via global_load_lds w/ XOR swizzle, dbuf. defer-max.
// Grid: bh fastest -> same-bh blocks land on same XCD (64%8==0), KV L2-resident.
__global__ __launch_bounds__(256) void attn_fwd(const u16* __restrict__ Q,
                                                const u16* __restrict__ K,
                                                const u16* __restrict__ Vt,
                                                u16* __restrict__ O) {
  __shared__ u16 Kl[2][64 * 64];   // 16 KB (dbuf)
  __shared__ u16 Vl[2][64 * 64];   // 16 KB (dbuf) -> 32 KB total
  const int t = threadIdx.x, lane = t & 63, wave = t >> 6;
  const int q = lane & 31, hi = lane >> 5;
  const int bh = blockIdx.x & 63;           // bh fastest
  const int qtile = 15 - (blockIdx.x >> 6); // heavy-first
  const int q0 = qtile * 128;
  const size_t rowbase = (size_t)(bh >> 4) * SEQ;
  const int hcol = (bh & 15) * DKH;
  const size_t vbase = (size_t)bh * DKH;
  const int qw = q0 + wave * 32;            // this wave's 32 q-rows
  const int nit = qtile * 2 + 2;

  auto stage = [&](int buf, int kv0) {
#pragma unroll
    for (int pp = 0; pp < 2; ++pp) {
      int chunk = pp * 256 + t;
      int r = chunk >> 3, cc = chunk & 7;
      int cs = cc ^ (r & 7);  // pre-swizzled global source; LDS linear
      GLD16(K + (rowbase + kv0 + r) * D_MODEL + hcol + cs * 8,
            &Kl[buf][(size_t)(pp * 256 + (t & ~63)) * 8]);
      GLD16(Vt + (vbase + r) * SEQ + kv0 + cs * 8,
            &Vl[buf][(size_t)(pp * 256 + (t & ~63)) * 8]);
    }
  };

  stage(0, 0);

  // Q B-frags: lane(q,hi) holds Q[qw+q][w*16 + hi*8 + i], w=0..3 (16 VGPR)
  bf16x8 qf[4];
#pragma unroll
  for (int w = 0; w < 4; ++w)
    qf[w] = *(const bf16x8*)&Q[(rowbase + qw + q) * D_MODEL + hcol + w * 16 + hi * 8];

  f32x16 ot0 = {}, ot1 = {};        // O^T: col q=lane&31, row d=crow(r,hi) (+32 for ot1)
  float mstate = -__builtin_inff();
  float lstate = 0.f;

  __syncthreads();
  int cur = 0;
  for (int it = 0; it < nit; ++it) {
    const int kv0 = it * 64;
    if (it + 1 < nit) stage(cur ^ 1, kv0 + 64);

    if (kv0 <= qw + 31) {  // wave-uniform causal participation
      // ---- S^T tiles: s0 = K[kv0..kv0+31] Q^T, s1 = K[kv0+32..63] Q^T
      f32x16 s0 = {}, s1 = {};
      __builtin_amdgcn_s_setprio(1);
#pragma unroll
      for (int w = 0; w < 4; ++w) {
        const int rk0 = q, rk1 = 32 + q;   // (32+q)&7 == q&7
        bf16x8 k0 = *(const bf16x8*)&Kl[cur][rk0 * 64 + (((2 * w + hi) ^ (rk0 & 7)) * 8)];
        bf16x8 k1 = *(const bf16x8*)&Kl[cur][rk1 * 64 + (((2 * w + hi) ^ (rk0 & 7)) * 8)];
        s0 = __builtin_amdgcn_mfma_f32_32x32x16_bf16(k0, qf[w], s0, 0, 0, 0);
        s1 = __builtin_amdgcn_mfma_f32_32x32x16_bf16(k1, qf[w], s1, 0, 0, 0);
      }
      __builtin_amdgcn_s_setprio(0);

      // ---- mask (diagonal tiles only): k = kv0 + {0,32} + crow(r,hi); q_g = qw+q
      const int qg = qw + q;
      if (kv0 + 63 > qw) {
#pragma unroll
        for (int r = 0; r < 16; ++r) {
          const int crow = (r & 3) + 8 * (r >> 2) + 4 * hi;
          if (kv0 + crow > qg) s0[r] = -__builtin_inff();
          if (kv0 + 32 + crow > qg) s1[r] = -__builtin_inff();
        }
      }

      // ---- lane-local max over 32 vals + 1 cross-half swap
      float pmax = fmaxf(s0[0], s0[1]);
#pragma unroll
      for (int r = 2; r < 16; ++r) pmax = fmaxf(pmax, s0[r]);
#pragma unroll
      for (int r = 0; r < 16; ++r) pmax = fmaxf(pmax, s1[r]);
      pmax = fmaxf(pmax, __shfl_xor(pmax, 32));

      // defer-max (T13), log2 domain: P bounded by 2^11.54 = e^8
      if (__any(pmax > mstate + 11.5416f)) {
        float mnew = fmaxf(mstate, pmax);
        float al = fexp2(mstate - mnew);  // first tile: exp2(-inf)=0
        mstate = mnew;
        lstate *= al;
#pragma unroll
        for (int r = 0; r < 16; ++r) { ot0[r] *= al; ot1[r] *= al; }
      }
      const float mm = mstate;

      // ---- exp (in place) + row-sum
      float lsum = 0.f;
#pragma unroll
      for (int r = 0; r < 16; ++r) { s0[r] = fexp2(s0[r] - mm); lsum += s0[r]; }
#pragma unroll
      for (int r = 0; r < 16; ++r) { s1[r] = fexp2(s1[r] - mm); lsum += s1[r]; }
      lsum += __shfl_xor(lsum, 32);
      lstate += lsum;

      // ---- P B-frags in-register (16 cvt_pk + 8 permlane32_swap)
      bf16x8 pb0 = make_pfrag<0>(s0);   // k in [kv0+0,16)
      bf16x8 pb1 = make_pfrag<8>(s0);   // [16,32)
      bf16x8 pb2 = make_pfrag<0>(s1);   // [32,48)
      bf16x8 pb3 = make_pfrag<8>(s1);   // [48,64)

      // ---- O^T += Vt P : A=Vt rows d (ot0: d=q(+0), ot1: d=32+q), B=P cols q
      __builtin_amdgcn_s_setprio(1);
#define PV_STEP(KB, PB)                                                                   \
      {                                                                                   \
        bf16x8 v0 = *(const bf16x8*)&Vl[cur][q * 64 + (((2 * (KB) + hi) ^ (q & 7)) * 8)]; \
        bf16x8 v1 = *(const bf16x8*)&Vl[cur][(32 + q) * 64 + (((2 * (KB) + hi) ^ (q & 7)) * 8)]; \
        ot0 = __builtin_amdgcn_mfma_f32_32x32x16_bf16(v0, PB, ot0, 0, 0, 0);              \
        ot1 = __builtin_amdgcn_mfma_f32_32x32x16_bf16(v1, PB, ot1, 0, 0, 0);              \
      }
      PV_STEP(0, pb0)
      PV_STEP(1, pb1)
      PV_STEP(2, pb2)
      PV_STEP(3, pb3)
#undef PV_STEP
      __builtin_amdgcn_s_setprio(0);
    }
    __syncthreads();
    cur ^= 1;
  }

  // ---- epilogue: O[qw+q][hcol+d] = O^T/l; reg r=4g+j -> d = j + 8g + 4hi (+32 for ot1)
  const float inv = 1.0f / lstate;
  u16* orow = &O[(rowbase + qw + q) * D_MODEL + hcol];
#pragma unroll
  for (int g2 = 0; g2 < 4; ++g2) {
    ushort4 a4 = make_ushort4(f2bf(ot0[4 * g2 + 0] * inv), f2bf(ot0[4 * g2 + 1] * inv),
                              f2bf(ot0[4 * g2 + 2] * inv), f2bf(ot0[4 * g2 + 3] * inv));
    *(ushort4*)&orow[8 * g2 + 4 * hi] = a4;
    ushort4 b4 = make_ushort4(f2bf(ot1[4 * g2 + 0] * inv), f2bf(ot1[4 * g2 + 1] * inv),
                              f2bf(ot1[4 * g2 + 2] * inv), f2bf(ot1[4 * g2 + 3] * inv));
    *(ushort4*)&orow[32 + 8 * g2 + 4 * hi] = b4;
  }
}

// ---------------------------------------------------------------- launch
extern "C" void kernel_launch(void* const* d_in, const int* in_sizes, int n_in,
                              void* d_out, int out_size, void* d_ws, size_t ws_size,
                              hipStream_t stream) {
  const float* x  = (const float*)d_in[0];
  const float* Wq = (const float*)d_in[1];
  const float* Wk = (const float*)d_in[2];
  const float* Wv = (const float*)d_in[3];
  const float* Wo = (const float*)d_in[4];
  float* out = (float*)d_out;

  u16* ws  = (u16*)d_ws;
  u16* xb  = ws;
  u16* wqb = xb + (size_t)NTOK * D_MODEL;
  u16* wkb = wqb + (size_t)D_MODEL * D_MODEL;
  u16* wvb = wkb + (size_t)D_MODEL * D_MODEL;
  u16* wob = wvb + (size_t)D_MODEL * D_MODEL;
  u16* Qb  = wob + (size_t)D_MODEL * D_MODEL;
  u16* Kb  = Qb + (size_t)NTOK * D_MODEL;
  u16* Vb  = Kb + (size_t)NTOK * D_MODEL;   // per-head V^T [B*H*64][SEQ]
  u16* Ob  = xb;  // reuse x's bf16 buffer after projections

  cvt_all<<<2048, 256, 0, stream>>>(x, Wq, Wk, Wv, Wo, xb, wqb, wkb, wvb, wob);

  gemm_qkv<<<1536, 256, 0, stream>>>(xb, wqb, wkb, wvb, Qb, Kb, Vb);

  attn_fwd<<<dim3(16 * 64), 256, 0, stream>>>(Qb, Kb, Vb, Ob);

  gemm_out<<<512, 256, 0, stream>>>(Ob, wob, out);
}